// Round 6
// baseline (405.913 us; speedup 1.0000x reference)
//
#include <hip/hip_runtime.h>

#define N1 16384
#define N2 4096
#define CC 128
#define KIN 384
#define HID 256

typedef unsigned short u16;
typedef unsigned int u32;

typedef _Float16 v8h __attribute__((ext_vector_type(8)));
typedef float v4f __attribute__((ext_vector_type(4)));

// ---------- workspace layout (bytes) ----------
// W0h  fp16 256x384           @ 0        (196608)
// W1h  fp16 256x256           @ 196608   (131072)
// sst  fp32 s0,t0,s1,t1 x256  @ 327680   (4096)
// xyz2q float4 B*N2           @ 331776   (262144)
// idx3 int B*N1*3             @ 593920   (786432)
// w3   fp32 B*N1*3            @ 1380352  (786432)
// p2t  fp32 B*N2*C            @ 2166784  (8388608)
// total = 10555392

__device__ __forceinline__ u16 f2h(float f) {
    _Float16 h = (_Float16)f;
    return __builtin_bit_cast(u16, h);
}

// =====================================================================
// Prep: convert weights to fp16, fold BN into scale/shift, build xyz2q
// =====================================================================
__global__ __launch_bounds__(256) void prep_kernel(
    const float* __restrict__ w0, const float* __restrict__ w1,
    const float* __restrict__ b0, const float* __restrict__ g0, const float* __restrict__ be0,
    const float* __restrict__ m0, const float* __restrict__ v0,
    const float* __restrict__ b1, const float* __restrict__ g1, const float* __restrict__ be1,
    const float* __restrict__ m1, const float* __restrict__ v1,
    const float* __restrict__ xyz2,
    u16* __restrict__ W0h, u16* __restrict__ W1h,
    float* __restrict__ sst, float4* __restrict__ xyz2q)
{
    int id = blockIdx.x * 256 + threadIdx.x;
    if (id < 98304) {
        W0h[id] = f2h(w0[id]);
    } else if (id < 163840) {
        int t = id - 98304;
        W1h[t] = f2h(w1[t]);
    } else if (id < 164352) {
        int t = id - 163840;
        int o = t & 255;
        if (t < 256) {
            float s = g0[o] * rsqrtf(v0[o] + 1e-5f);
            sst[o]       = s;
            sst[256 + o] = (b0[o] - m0[o]) * s + be0[o];
        } else {
            float s = g1[o] * rsqrtf(v1[o] + 1e-5f);
            sst[512 + o] = s;
            sst[768 + o] = (b1[o] - m1[o]) * s + be1[o];
        }
    } else if (id < 180736) {
        int t = id - 164352;  // b*N2+n
        float x = xyz2[(size_t)t * 3 + 0];
        float y = xyz2[(size_t)t * 3 + 1];
        float z = xyz2[(size_t)t * 3 + 2];
        xyz2q[t] = make_float4(x, y, z, fmaf(x, x, fmaf(y, y, z * z)));
    }
}

// =====================================================================
// Transpose points2 (B,C,N2) -> p2t (B,N2,C), LDS-tiled
// =====================================================================
__global__ __launch_bounds__(256) void transpose_kernel(
    const float* __restrict__ points2, float* __restrict__ p2t)
{
    __shared__ float tile[32][65];
    int n20 = blockIdx.x * 64;
    int c0  = blockIdx.y * 32;
    int b   = blockIdx.z;
    int tid = threadIdx.x;
    int n2i = tid & 63, ci = tid >> 6;
    for (int cc = ci; cc < 32; cc += 4)
        tile[cc][n2i] = points2[((size_t)b * CC + (c0 + cc)) * N2 + n20 + n2i];
    __syncthreads();
    int co = tid & 31, ro = tid >> 5;
    for (int rr = ro; rr < 64; rr += 8)
        p2t[((size_t)b * N2 + n20 + rr) * CC + c0 + co] = tile[co][rr];
}

// =====================================================================
// 3-NN + inverse-distance weights
// 256 thr / block, 64 queries / block, 4 queries / thread,
// 16-way candidate split; candidates staged in 2 stages x 2048 float4
// (32 KB LDS). Grid 1024 = 4 blocks/CU.
// __launch_bounds__(256,4): min 4 waves/EU -> VGPR cap 128 (state needs
// ~88; without this the default heuristic squeezed to 44 VGPR and spilled
// 100 MB of scratch -- R5 counter evidence).
// Inner loop branchless: med3/min distance network + cndmask indices.
// =====================================================================
__device__ __forceinline__ void ins3lex(float t, int j,
    float& d0, float& d1, float& d2, int& i0, int& i1, int& i2)
{
    if (t < d2 || (t == d2 && j < i2)) {
        if (t < d1 || (t == d1 && j < i1)) {
            d2 = d1; i2 = i1;
            if (t < d0 || (t == d0 && j < i0)) { d1 = d0; i1 = i0; d0 = t; i0 = j; }
            else                               { d1 = t;  i1 = j; }
        } else { d2 = t; i2 = j; }
    }
}

__global__ __launch_bounds__(256, 4) void knn_kernel(
    const float* __restrict__ xyz1, const float4* __restrict__ xyz2q,
    int* __restrict__ idx3, float* __restrict__ w3)
{
    __shared__ float4 slds[2048];   // 32768 B

    int tid = threadIdx.x;
    int b   = blockIdx.y;
    int n0  = blockIdx.x * 64;

    int s  = tid & 15;      // candidate split (lane bits 0..3)
    int g  = tid >> 4;      // query group 0..15
    int p0 = n0 + g * 4;

    float ax[4], ay[4], az[4], pp[4];
#pragma unroll
    for (int q = 0; q < 4; ++q) {
        size_t pb = ((size_t)b * N1 + p0 + q) * 3;
        float x = xyz1[pb], y = xyz1[pb + 1], z = xyz1[pb + 2];
        ax[q] = -2.f * x; ay[q] = -2.f * y; az[q] = -2.f * z;
        pp[q] = fmaf(x, x, fmaf(y, y, z * z));
    }

    float d0[4], d1[4], d2[4];
    int   i0[4], i1[4], i2[4];
#pragma unroll
    for (int q = 0; q < 4; ++q) {
        d0[q] = 1e30f; d1[q] = 1e30f; d2[q] = 1e30f;
        i0[q] = 0;     i1[q] = 0;     i2[q] = 0;
    }

#pragma unroll
    for (int stage = 0; stage < 2; ++stage) {
        int base = stage * 2048;
        // stage candidates to LDS (coalesced 16B)
        for (int i = tid; i < 2048; i += 256)
            slds[i] = xyz2q[(size_t)b * N2 + base + i];
        __syncthreads();

        // thread s scans candidates s, s+16, ... (ascending across stages ->
        // strict < keeps lowest-index-on-tie, matching stable top_k).
#pragma unroll 4
        for (int k = 0; k < 2048 / 16; ++k) {
            int c = s + (k << 4);
            float4 v = slds[c];
            int cand = base + c;
#pragma unroll
            for (int q = 0; q < 4; ++q) {
                float t = fmaf(ax[q], v.x, fmaf(ay[q], v.y, fmaf(az[q], v.z, v.w)));
                // branchless top-3 insert (v_cmp/v_cndmask/v_med3)
                bool c0 = t < d0[q];
                bool c1 = t < d1[q];
                bool c2 = t < d2[q];
                i2[q] = c1 ? i1[q] : (c2 ? cand : i2[q]);   // uses old i1
                i1[q] = c0 ? i0[q] : (c1 ? cand : i1[q]);   // uses old i0
                i0[q] = c0 ? cand : i0[q];
                d2[q] = __builtin_amdgcn_fmed3f(d1[q], t, d2[q]);  // old d1
                d1[q] = __builtin_amdgcn_fmed3f(d0[q], t, d1[q]);  // old d0
                d0[q] = fminf(t, d0[q]);
            }
        }
        __syncthreads();   // protect LDS overwrite by next stage
    }

    // butterfly merge across the 16 splits (lex tie-break by true index)
#pragma unroll
    for (int st = 1; st <= 8; st <<= 1) {
#pragma unroll
        for (int q = 0; q < 4; ++q) {
            float e0 = __shfl_xor(d0[q], st, 64);
            float e1 = __shfl_xor(d1[q], st, 64);
            float e2 = __shfl_xor(d2[q], st, 64);
            int   j0 = __shfl_xor(i0[q], st, 64);
            int   j1 = __shfl_xor(i1[q], st, 64);
            int   j2 = __shfl_xor(i2[q], st, 64);
            ins3lex(e0, j0, d0[q], d1[q], d2[q], i0[q], i1[q], i2[q]);
            ins3lex(e1, j1, d0[q], d1[q], d2[q], i0[q], i1[q], i2[q]);
            ins3lex(e2, j2, d0[q], d1[q], d2[q], i0[q], i1[q], i2[q]);
        }
    }

    if (s == 0) {
#pragma unroll
        for (int q = 0; q < 4; ++q) {
            float r0 = 1.f / (d0[q] + pp[q]);
            float r1 = 1.f / (d1[q] + pp[q]);
            float r2 = 1.f / (d2[q] + pp[q]);
            float inv = 1.f / (r0 + r1 + r2);
            size_t o3 = ((size_t)b * N1 + p0 + q) * 3;
            idx3[o3]     = i0[q];
            idx3[o3 + 1] = i1[q];
            idx3[o3 + 2] = i2[q];
            w3[o3]     = r0 * inv;
            w3[o3 + 1] = r1 * inv;
            w3[o3 + 2] = r2 * inv;
        }
    }
}

// =====================================================================
// Fused interpolate + concat + MLP(384->256->256, BN+ReLU) + channel max
// block = 256 thr (4 waves, 2x2 over o/p), 64 points per block
// =====================================================================
__global__ __launch_bounds__(256, 2) void mlp_kernel(
    const float* __restrict__ points1, const float* __restrict__ pointsb1,
    const float4* __restrict__ p2t4,
    const int* __restrict__ idx3, const float* __restrict__ w3,
    const uint4* __restrict__ W0v, const uint4* __restrict__ W1v,
    const float* __restrict__ sst, float* __restrict__ out)
{
    // x: 64 rows x 384 fp16, 16B-chunk swizzled by (p&7); h1 overlays (64x256)
    __shared__ __align__(16) u16 sx[64 * KIN];   // 49152 B
    __shared__ float sred[2][64];
    __shared__ int   s_idx[192];
    __shared__ float s_w[192];

    int tid = threadIdx.x;
    int b   = blockIdx.y;
    int n0  = blockIdx.x * 64;

    if (tid < 192) {
        size_t gi = ((size_t)b * N1 + n0) * 3 + tid;
        s_idx[tid] = idx3[gi];
        s_w[tid]   = w3[gi];
    }
    __syncthreads();

    // ---- stage x rows 0..127 (points1) ----
    for (int i = tid; i < 2048; i += 256) {
        int p = i & 63, r4 = (i >> 6) * 4;
        size_t base = ((size_t)b * CC + r4) * N1 + n0 + p;
        float a0 = points1[base];
        float a1 = points1[base + (size_t)N1];
        float a2 = points1[base + (size_t)2 * N1];
        float a3 = points1[base + (size_t)3 * N1];
        u32 lo = f2h(a0) | ((u32)f2h(a1) << 16);
        u32 hi = f2h(a2) | ((u32)f2h(a3) << 16);
        int chunk = (r4 >> 3) ^ (p & 7);
        *(uint2*)&sx[p * KIN + chunk * 8 + (r4 & 7)] = make_uint2(lo, hi);
    }
    // ---- stage x rows 256..383 (points_b1) ----
    for (int i = tid; i < 2048; i += 256) {
        int p = i & 63, r4 = (i >> 6) * 4;
        size_t base = ((size_t)b * CC + r4) * N1 + n0 + p;
        float a0 = pointsb1[base];
        float a1 = pointsb1[base + (size_t)N1];
        float a2 = pointsb1[base + (size_t)2 * N1];
        float a3 = pointsb1[base + (size_t)3 * N1];
        int k4 = 256 + r4;
        u32 lo = f2h(a0) | ((u32)f2h(a1) << 16);
        u32 hi = f2h(a2) | ((u32)f2h(a3) << 16);
        int chunk = (k4 >> 3) ^ (p & 7);
        *(uint2*)&sx[p * KIN + chunk * 8 + (k4 & 7)] = make_uint2(lo, hi);
    }
    // ---- stage x rows 128..255: 3-NN interpolation from p2t rows ----
    for (int i = tid; i < 2048; i += 256) {
        int c4 = i & 31, p = i >> 5;
        float w0w = s_w[p * 3 + 0], w1w = s_w[p * 3 + 1], w2w = s_w[p * 3 + 2];
        float4 f0 = p2t4[((size_t)b * N2 + s_idx[p * 3 + 0]) * 32 + c4];
        float4 f1 = p2t4[((size_t)b * N2 + s_idx[p * 3 + 1]) * 32 + c4];
        float4 f2 = p2t4[((size_t)b * N2 + s_idx[p * 3 + 2]) * 32 + c4];
        float e0 = fmaf(w0w, f0.x, fmaf(w1w, f1.x, w2w * f2.x));
        float e1 = fmaf(w0w, f0.y, fmaf(w1w, f1.y, w2w * f2.y));
        float e2 = fmaf(w0w, f0.z, fmaf(w1w, f1.z, w2w * f2.z));
        float e3 = fmaf(w0w, f0.w, fmaf(w1w, f1.w, w2w * f2.w));
        int k4 = 128 + c4 * 4;
        u32 lo = f2h(e0) | ((u32)f2h(e1) << 16);
        u32 hi = f2h(e2) | ((u32)f2h(e3) << 16);
        int chunk = (k4 >> 3) ^ (p & 7);
        *(uint2*)&sx[p * KIN + chunk * 8 + (k4 & 7)] = make_uint2(lo, hi);
    }
    __syncthreads();

    int lane = tid & 63, wave = tid >> 6;
    int wo = wave >> 1, wp = wave & 1;      // o-half, p-half
    int ml = lane & 15, ql = lane >> 4;     // frag row/col, quad
    int p0  = wp * 32 + ml;                 // p for pt=0 (pt=1: +16)
    int px7 = ml & 7;                       // == p&7 for both pt

    // ---------------- GEMM1: h1 = W0 @ x ----------------
    v4f acc1[8][2];
#pragma unroll
    for (int ot = 0; ot < 8; ++ot)
        for (int pt = 0; pt < 2; ++pt)
            acc1[ot][pt] = (v4f){0.f, 0.f, 0.f, 0.f};

#pragma unroll
    for (int s = 0; s < 12; ++s) {
        int kc = s * 4 + ql;
        int pc = (kc ^ px7) * 8;
        v8h bf0 = __builtin_bit_cast(v8h, *(const uint4*)&sx[p0 * KIN + pc]);
        v8h bf1 = __builtin_bit_cast(v8h, *(const uint4*)&sx[(p0 + 16) * KIN + pc]);
#pragma unroll
        for (int ot = 0; ot < 8; ++ot) {
            int o = wo * 128 + ot * 16 + ml;
            v8h af = __builtin_bit_cast(v8h, W0v[o * 48 + kc]);
            acc1[ot][0] = __builtin_amdgcn_mfma_f32_16x16x32_f16(af, bf0, acc1[ot][0], 0, 0, 0);
            acc1[ot][1] = __builtin_amdgcn_mfma_f32_16x16x32_f16(af, bf1, acc1[ot][1], 0, 0, 0);
        }
    }
    __syncthreads();   // all x reads done before h1 overlays sx

    // epilogue 1: BN+ReLU -> fp16 h1[p][o] (row stride 256, swizzled)
    const float* s0v = sst;
    const float* t0v = sst + 256;
#pragma unroll
    for (int ot = 0; ot < 8; ++ot) {
        int o0 = wo * 128 + ot * 16 + ql * 4;
        float sc0 = s0v[o0], sc1 = s0v[o0 + 1], sc2 = s0v[o0 + 2], sc3 = s0v[o0 + 3];
        float sh0 = t0v[o0], sh1 = t0v[o0 + 1], sh2 = t0v[o0 + 2], sh3 = t0v[o0 + 3];
        int chunk = ((o0 >> 3) ^ px7);
#pragma unroll
        for (int pt = 0; pt < 2; ++pt) {
            int p = p0 + pt * 16;
            float z0 = fmaxf(fmaf(acc1[ot][pt][0], sc0, sh0), 0.f);
            float z1 = fmaxf(fmaf(acc1[ot][pt][1], sc1, sh1), 0.f);
            float z2 = fmaxf(fmaf(acc1[ot][pt][2], sc2, sh2), 0.f);
            float z3 = fmaxf(fmaf(acc1[ot][pt][3], sc3, sh3), 0.f);
            u32 lo = f2h(z0) | ((u32)f2h(z1) << 16);
            u32 hi = f2h(z2) | ((u32)f2h(z3) << 16);
            *(uint2*)&sx[p * HID + chunk * 8 + (o0 & 7)] = make_uint2(lo, hi);
        }
    }
    __syncthreads();

    // ---------------- GEMM2: h2 = W1 @ h1 ----------------
    v4f acc2[8][2];
#pragma unroll
    for (int ot = 0; ot < 8; ++ot)
        for (int pt = 0; pt < 2; ++pt)
            acc2[ot][pt] = (v4f){0.f, 0.f, 0.f, 0.f};

#pragma unroll
    for (int s = 0; s < 8; ++s) {
        int kc = s * 4 + ql;
        int pc = (kc ^ px7) * 8;
        v8h bf0 = __builtin_bit_cast(v8h, *(const uint4*)&sx[p0 * HID + pc]);
        v8h bf1 = __builtin_bit_cast(v8h, *(const uint4*)&sx[(p0 + 16) * HID + pc]);
#pragma unroll
        for (int ot = 0; ot < 8; ++ot) {
            int o = wo * 128 + ot * 16 + ml;
            v8h af = __builtin_bit_cast(v8h, W1v[o * 32 + kc]);
            acc2[ot][0] = __builtin_amdgcn_mfma_f32_16x16x32_f16(af, bf0, acc2[ot][0], 0, 0, 0);
            acc2[ot][1] = __builtin_amdgcn_mfma_f32_16x16x32_f16(af, bf1, acc2[ot][1], 0, 0, 0);
        }
    }

    // epilogue 2: BN + ReLU (via max with 0) + channel max
    const float* s1v = sst + 512;
    const float* t1v = sst + 768;
    float mx0 = 0.f, mx1 = 0.f;   // relu floor = 0
#pragma unroll
    for (int ot = 0; ot < 8; ++ot) {
        int o0 = wo * 128 + ot * 16 + ql * 4;
#pragma unroll
        for (int r = 0; r < 4; ++r) {
            float sc = s1v[o0 + r], sh = t1v[o0 + r];
            mx0 = fmaxf(mx0, fmaf(acc2[ot][0][r], sc, sh));
            mx1 = fmaxf(mx1, fmaf(acc2[ot][1][r], sc, sh));
        }
    }
    mx0 = fmaxf(mx0, __shfl_xor(mx0, 16, 64));
    mx0 = fmaxf(mx0, __shfl_xor(mx0, 32, 64));
    mx1 = fmaxf(mx1, __shfl_xor(mx1, 16, 64));
    mx1 = fmaxf(mx1, __shfl_xor(mx1, 32, 64));
    if (lane < 16) {
        sred[wo][wp * 32 + lane]      = mx0;
        sred[wo][wp * 32 + 16 + lane] = mx1;
    }
    __syncthreads();
    if (tid < 64)
        out[(size_t)b * N1 + n0 + tid] = fmaxf(sred[0][tid], sred[1][tid]);
}

// =====================================================================
extern "C" void kernel_launch(void* const* d_in, const int* in_sizes, int n_in,
                              void* d_out, int out_size, void* d_ws, size_t ws_size,
                              hipStream_t stream)
{
    const float* xyz1     = (const float*)d_in[0];
    const float* xyz2     = (const float*)d_in[1];
    const float* points2  = (const float*)d_in[2];
    const float* points1  = (const float*)d_in[3];
    const float* pointsb1 = (const float*)d_in[4];
    const float* w0   = (const float*)d_in[5];
    const float* b0   = (const float*)d_in[6];
    const float* g0   = (const float*)d_in[7];
    const float* be0  = (const float*)d_in[8];
    const float* m0   = (const float*)d_in[9];
    const float* v0   = (const float*)d_in[10];
    const float* w1   = (const float*)d_in[11];
    const float* b1   = (const float*)d_in[12];
    const float* g1   = (const float*)d_in[13];
    const float* be1  = (const float*)d_in[14];
    const float* m1   = (const float*)d_in[15];
    const float* v1   = (const float*)d_in[16];
    float* out = (float*)d_out;

    char* ws = (char*)d_ws;
    u16*    W0h   = (u16*)(ws + 0);
    u16*    W1h   = (u16*)(ws + 196608);
    float*  sst   = (float*)(ws + 327680);
    float4* xyz2q = (float4*)(ws + 331776);
    int*    idx3  = (int*)(ws + 593920);
    float*  w3    = (float*)(ws + 1380352);
    float*  p2t   = (float*)(ws + 2166784);

    prep_kernel<<<706, 256, 0, stream>>>(w0, w1, b0, g0, be0, m0, v0,
                                         b1, g1, be1, m1, v1, xyz2,
                                         W0h, W1h, sst, xyz2q);
    transpose_kernel<<<dim3(64, 4, 4), 256, 0, stream>>>(points2, p2t);
    knn_kernel<<<dim3(256, 4), 256, 0, stream>>>(xyz1, xyz2q, idx3, w3);
    mlp_kernel<<<dim3(256, 4), 256, 0, stream>>>(points1, pointsb1,
                                                 (const float4*)p2t, idx3, w3,
                                                 (const uint4*)W0h, (const uint4*)W1h,
                                                 sst, out);
}

// Round 7
// 370.671 us; speedup vs baseline: 1.0951x; 1.0951x over previous
//
#include <hip/hip_runtime.h>

#define N1 16384
#define N2 4096
#define CC 128
#define KIN 384
#define HID 256

typedef unsigned short u16;
typedef unsigned int u32;

typedef _Float16 v8h __attribute__((ext_vector_type(8)));
typedef float v4f __attribute__((ext_vector_type(4)));

// ---------- workspace layout (bytes) ----------
// W0h  fp16 256x384           @ 0        (196608)
// W1h  fp16 256x256           @ 196608   (131072)
// sst  fp32 s0,t0,s1,t1 x256  @ 327680   (4096)
// xyz2q float4 B*N2           @ 331776   (262144)
// idx3 int B*N1*3             @ 593920   (786432)
// w3   fp32 B*N1*3            @ 1380352  (786432)
// p2t  fp32 B*N2*C            @ 2166784  (8388608)
// total = 10555392

__device__ __forceinline__ u16 f2h(float f) {
    _Float16 h = (_Float16)f;
    return __builtin_bit_cast(u16, h);
}

// =====================================================================
// Prep: convert weights to fp16, fold BN into scale/shift, build xyz2q
// =====================================================================
__global__ __launch_bounds__(256) void prep_kernel(
    const float* __restrict__ w0, const float* __restrict__ w1,
    const float* __restrict__ b0, const float* __restrict__ g0, const float* __restrict__ be0,
    const float* __restrict__ m0, const float* __restrict__ v0,
    const float* __restrict__ b1, const float* __restrict__ g1, const float* __restrict__ be1,
    const float* __restrict__ m1, const float* __restrict__ v1,
    const float* __restrict__ xyz2,
    u16* __restrict__ W0h, u16* __restrict__ W1h,
    float* __restrict__ sst, float4* __restrict__ xyz2q)
{
    int id = blockIdx.x * 256 + threadIdx.x;
    if (id < 98304) {
        W0h[id] = f2h(w0[id]);
    } else if (id < 163840) {
        int t = id - 98304;
        W1h[t] = f2h(w1[t]);
    } else if (id < 164352) {
        int t = id - 163840;
        int o = t & 255;
        if (t < 256) {
            float s = g0[o] * rsqrtf(v0[o] + 1e-5f);
            sst[o]       = s;
            sst[256 + o] = (b0[o] - m0[o]) * s + be0[o];
        } else {
            float s = g1[o] * rsqrtf(v1[o] + 1e-5f);
            sst[512 + o] = s;
            sst[768 + o] = (b1[o] - m1[o]) * s + be1[o];
        }
    } else if (id < 180736) {
        int t = id - 164352;  // b*N2+n
        float x = xyz2[(size_t)t * 3 + 0];
        float y = xyz2[(size_t)t * 3 + 1];
        float z = xyz2[(size_t)t * 3 + 2];
        xyz2q[t] = make_float4(x, y, z, fmaf(x, x, fmaf(y, y, z * z)));
    }
}

// =====================================================================
// Transpose points2 (B,C,N2) -> p2t (B,N2,C), LDS-tiled
// =====================================================================
__global__ __launch_bounds__(256) void transpose_kernel(
    const float* __restrict__ points2, float* __restrict__ p2t)
{
    __shared__ float tile[32][65];
    int n20 = blockIdx.x * 64;
    int c0  = blockIdx.y * 32;
    int b   = blockIdx.z;
    int tid = threadIdx.x;
    int n2i = tid & 63, ci = tid >> 6;
    for (int cc = ci; cc < 32; cc += 4)
        tile[cc][n2i] = points2[((size_t)b * CC + (c0 + cc)) * N2 + n20 + n2i];
    __syncthreads();
    int co = tid & 31, ro = tid >> 5;
    for (int rr = ro; rr < 64; rr += 8)
        p2t[((size_t)b * N2 + n20 + rr) * CC + c0 + co] = tile[co][rr];
}

// =====================================================================
// 3-NN + inverse-distance weights
// 256 thr / block, 64 queries / block, 4 queries / thread (named scalars,
// no arrays -> SROA-proof), 16-way candidate split; candidates staged in
// 2 stages x 2048 float4 (32 KB LDS). Grid 1024 = 4 blocks/CU.
// amdgpu_waves_per_eu(4,4): pins scheduler occupancy target to 4 waves/EU
// -> 128-VGPR budget; R5/R6 evidence: without the max, allocator squeezes
// to 44 VGPR and spills ~80 MB scratch.
// =====================================================================

// branchless top-3 insert (v_cmp/v_cndmask/v_med3); ascending scan + strict
// < keeps lowest-index-on-tie, matching stable top_k.
#define BINS(t, cand, D0, D1, D2, I0, I1, I2) do {                    \
    bool c0 = (t) < (D0);                                             \
    bool c1 = (t) < (D1);                                             \
    bool c2 = (t) < (D2);                                             \
    I2 = c1 ? (I1) : (c2 ? (cand) : (I2));   /* old I1 */             \
    I1 = c0 ? (I0) : (c1 ? (cand) : (I1));   /* old I0 */             \
    I0 = c0 ? (cand) : (I0);                                          \
    D2 = __builtin_amdgcn_fmed3f((D1), (t), (D2));  /* old D1 */      \
    D1 = __builtin_amdgcn_fmed3f((D0), (t), (D1));  /* old D0 */      \
    D0 = fminf((t), (D0));                                            \
} while (0)

// lexicographic insert for the merge (tie -> lower index wins). Conditions
// precomputed vs old values (equivalent to nested form: mutations never
// precede the compares they feed).
#define INS3LEX(t, j, D0, D1, D2, I0, I1, I2) do {                    \
    bool lt2 = (t) < (D2) || ((t) == (D2) && (j) < (I2));             \
    bool lt1 = (t) < (D1) || ((t) == (D1) && (j) < (I1));             \
    bool lt0 = (t) < (D0) || ((t) == (D0) && (j) < (I0));             \
    if (lt2) {                                                        \
        if (lt1) {                                                    \
            D2 = (D1); I2 = (I1);                                     \
            if (lt0) { D1 = (D0); I1 = (I0); D0 = (t); I0 = (j); }    \
            else     { D1 = (t); I1 = (j); }                          \
        } else { D2 = (t); I2 = (j); }                                \
    }                                                                 \
} while (0)

#define MERGE_STEP(st, D0, D1, D2, I0, I1, I2) do {                   \
    float e0 = __shfl_xor((D0), (st), 64);                            \
    float e1 = __shfl_xor((D1), (st), 64);                            \
    float e2 = __shfl_xor((D2), (st), 64);                            \
    int   j0 = __shfl_xor((I0), (st), 64);                            \
    int   j1 = __shfl_xor((I1), (st), 64);                            \
    int   j2 = __shfl_xor((I2), (st), 64);                            \
    INS3LEX(e0, j0, D0, D1, D2, I0, I1, I2);                          \
    INS3LEX(e1, j1, D0, D1, D2, I0, I1, I2);                          \
    INS3LEX(e2, j2, D0, D1, D2, I0, I1, I2);                          \
} while (0)

#define KNN_OUT(Q, D0, D1, D2, I0, I1, I2, PP) do {                   \
    float r0 = 1.f / ((D0) + (PP));                                   \
    float r1 = 1.f / ((D1) + (PP));                                   \
    float r2 = 1.f / ((D2) + (PP));                                   \
    float inv = 1.f / (r0 + r1 + r2);                                 \
    size_t o3 = ((size_t)b * N1 + p0 + (Q)) * 3;                      \
    idx3[o3]     = (I0);                                              \
    idx3[o3 + 1] = (I1);                                              \
    idx3[o3 + 2] = (I2);                                              \
    w3[o3]     = r0 * inv;                                            \
    w3[o3 + 1] = r1 * inv;                                            \
    w3[o3 + 2] = r2 * inv;                                            \
} while (0)

__global__ __launch_bounds__(256)
__attribute__((amdgpu_waves_per_eu(4, 4)))
void knn_kernel(
    const float* __restrict__ xyz1, const float4* __restrict__ xyz2q,
    int* __restrict__ idx3, float* __restrict__ w3)
{
    __shared__ float4 slds[2048];   // 32768 B

    int tid = threadIdx.x;
    int b   = blockIdx.y;
    int n0  = blockIdx.x * 64;

    int s  = tid & 15;      // candidate split (lane bits 0..3)
    int g  = tid >> 4;      // query group 0..15
    int p0 = n0 + g * 4;

    size_t pb = ((size_t)b * N1 + p0) * 3;
    float x0 = xyz1[pb + 0],  y0 = xyz1[pb + 1],  z0 = xyz1[pb + 2];
    float x1 = xyz1[pb + 3],  y1 = xyz1[pb + 4],  z1 = xyz1[pb + 5];
    float x2 = xyz1[pb + 6],  y2 = xyz1[pb + 7],  z2 = xyz1[pb + 8];
    float x3 = xyz1[pb + 9],  y3 = xyz1[pb + 10], z3 = xyz1[pb + 11];
    float ax0 = -2.f * x0, ay0 = -2.f * y0, az0 = -2.f * z0;
    float ax1 = -2.f * x1, ay1 = -2.f * y1, az1 = -2.f * z1;
    float ax2 = -2.f * x2, ay2 = -2.f * y2, az2 = -2.f * z2;
    float ax3 = -2.f * x3, ay3 = -2.f * y3, az3 = -2.f * z3;
    float pp0 = fmaf(x0, x0, fmaf(y0, y0, z0 * z0));
    float pp1 = fmaf(x1, x1, fmaf(y1, y1, z1 * z1));
    float pp2 = fmaf(x2, x2, fmaf(y2, y2, z2 * z2));
    float pp3 = fmaf(x3, x3, fmaf(y3, y3, z3 * z3));

    float da0 = 1e30f, da1 = 1e30f, da2 = 1e30f;
    float db0 = 1e30f, db1 = 1e30f, db2 = 1e30f;
    float dc0 = 1e30f, dc1 = 1e30f, dc2 = 1e30f;
    float dd0 = 1e30f, dd1 = 1e30f, dd2 = 1e30f;
    int   ia0 = 0, ia1 = 0, ia2 = 0;
    int   ib0 = 0, ib1 = 0, ib2 = 0;
    int   ic0 = 0, ic1 = 0, ic2 = 0;
    int   id0 = 0, id1 = 0, id2 = 0;

#pragma unroll
    for (int stage = 0; stage < 2; ++stage) {
        int base = stage * 2048;
        // stage candidates to LDS (coalesced 16B)
        for (int i = tid; i < 2048; i += 256)
            slds[i] = xyz2q[(size_t)b * N2 + base + i];
        __syncthreads();

        // thread s scans candidates s, s+16, ... ascending across stages
#pragma unroll 4
        for (int k = 0; k < 2048 / 16; ++k) {
            int c = s + (k << 4);
            float4 v = slds[c];
            int cand = base + c;
            float t0 = fmaf(ax0, v.x, fmaf(ay0, v.y, fmaf(az0, v.z, v.w)));
            float t1 = fmaf(ax1, v.x, fmaf(ay1, v.y, fmaf(az1, v.z, v.w)));
            float t2 = fmaf(ax2, v.x, fmaf(ay2, v.y, fmaf(az2, v.z, v.w)));
            float t3 = fmaf(ax3, v.x, fmaf(ay3, v.y, fmaf(az3, v.z, v.w)));
            BINS(t0, cand, da0, da1, da2, ia0, ia1, ia2);
            BINS(t1, cand, db0, db1, db2, ib0, ib1, ib2);
            BINS(t2, cand, dc0, dc1, dc2, ic0, ic1, ic2);
            BINS(t3, cand, dd0, dd1, dd2, id0, id1, id2);
        }
        __syncthreads();   // protect LDS overwrite by next stage
    }

    // butterfly merge across the 16 splits (lex tie-break by true index)
#pragma unroll
    for (int st = 1; st <= 8; st <<= 1) {
        MERGE_STEP(st, da0, da1, da2, ia0, ia1, ia2);
        MERGE_STEP(st, db0, db1, db2, ib0, ib1, ib2);
        MERGE_STEP(st, dc0, dc1, dc2, ic0, ic1, ic2);
        MERGE_STEP(st, dd0, dd1, dd2, id0, id1, id2);
    }

    if (s == 0) {
        KNN_OUT(0, da0, da1, da2, ia0, ia1, ia2, pp0);
        KNN_OUT(1, db0, db1, db2, ib0, ib1, ib2, pp1);
        KNN_OUT(2, dc0, dc1, dc2, ic0, ic1, ic2, pp2);
        KNN_OUT(3, dd0, dd1, dd2, id0, id1, id2, pp3);
    }
}

// =====================================================================
// Fused interpolate + concat + MLP(384->256->256, BN+ReLU) + channel max
// block = 256 thr (4 waves, 2x2 over o/p), 64 points per block
// =====================================================================
__global__ __launch_bounds__(256, 2) void mlp_kernel(
    const float* __restrict__ points1, const float* __restrict__ pointsb1,
    const float4* __restrict__ p2t4,
    const int* __restrict__ idx3, const float* __restrict__ w3,
    const uint4* __restrict__ W0v, const uint4* __restrict__ W1v,
    const float* __restrict__ sst, float* __restrict__ out)
{
    // x: 64 rows x 384 fp16, 16B-chunk swizzled by (p&7); h1 overlays (64x256)
    __shared__ __align__(16) u16 sx[64 * KIN];   // 49152 B
    __shared__ float sred[2][64];
    __shared__ int   s_idx[192];
    __shared__ float s_w[192];

    int tid = threadIdx.x;
    int b   = blockIdx.y;
    int n0  = blockIdx.x * 64;

    if (tid < 192) {
        size_t gi = ((size_t)b * N1 + n0) * 3 + tid;
        s_idx[tid] = idx3[gi];
        s_w[tid]   = w3[gi];
    }
    __syncthreads();

    // ---- stage x rows 0..127 (points1) ----
    for (int i = tid; i < 2048; i += 256) {
        int p = i & 63, r4 = (i >> 6) * 4;
        size_t base = ((size_t)b * CC + r4) * N1 + n0 + p;
        float a0 = points1[base];
        float a1 = points1[base + (size_t)N1];
        float a2 = points1[base + (size_t)2 * N1];
        float a3 = points1[base + (size_t)3 * N1];
        u32 lo = f2h(a0) | ((u32)f2h(a1) << 16);
        u32 hi = f2h(a2) | ((u32)f2h(a3) << 16);
        int chunk = (r4 >> 3) ^ (p & 7);
        *(uint2*)&sx[p * KIN + chunk * 8 + (r4 & 7)] = make_uint2(lo, hi);
    }
    // ---- stage x rows 256..383 (points_b1) ----
    for (int i = tid; i < 2048; i += 256) {
        int p = i & 63, r4 = (i >> 6) * 4;
        size_t base = ((size_t)b * CC + r4) * N1 + n0 + p;
        float a0 = pointsb1[base];
        float a1 = pointsb1[base + (size_t)N1];
        float a2 = pointsb1[base + (size_t)2 * N1];
        float a3 = pointsb1[base + (size_t)3 * N1];
        int k4 = 256 + r4;
        u32 lo = f2h(a0) | ((u32)f2h(a1) << 16);
        u32 hi = f2h(a2) | ((u32)f2h(a3) << 16);
        int chunk = (k4 >> 3) ^ (p & 7);
        *(uint2*)&sx[p * KIN + chunk * 8 + (k4 & 7)] = make_uint2(lo, hi);
    }
    // ---- stage x rows 128..255: 3-NN interpolation from p2t rows ----
    for (int i = tid; i < 2048; i += 256) {
        int c4 = i & 31, p = i >> 5;
        float w0w = s_w[p * 3 + 0], w1w = s_w[p * 3 + 1], w2w = s_w[p * 3 + 2];
        float4 f0 = p2t4[((size_t)b * N2 + s_idx[p * 3 + 0]) * 32 + c4];
        float4 f1 = p2t4[((size_t)b * N2 + s_idx[p * 3 + 1]) * 32 + c4];
        float4 f2 = p2t4[((size_t)b * N2 + s_idx[p * 3 + 2]) * 32 + c4];
        float e0 = fmaf(w0w, f0.x, fmaf(w1w, f1.x, w2w * f2.x));
        float e1 = fmaf(w0w, f0.y, fmaf(w1w, f1.y, w2w * f2.y));
        float e2 = fmaf(w0w, f0.z, fmaf(w1w, f1.z, w2w * f2.z));
        float e3 = fmaf(w0w, f0.w, fmaf(w1w, f1.w, w2w * f2.w));
        int k4 = 128 + c4 * 4;
        u32 lo = f2h(e0) | ((u32)f2h(e1) << 16);
        u32 hi = f2h(e2) | ((u32)f2h(e3) << 16);
        int chunk = (k4 >> 3) ^ (p & 7);
        *(uint2*)&sx[p * KIN + chunk * 8 + (k4 & 7)] = make_uint2(lo, hi);
    }
    __syncthreads();

    int lane = tid & 63, wave = tid >> 6;
    int wo = wave >> 1, wp = wave & 1;      // o-half, p-half
    int ml = lane & 15, ql = lane >> 4;     // frag row/col, quad
    int p0  = wp * 32 + ml;                 // p for pt=0 (pt=1: +16)
    int px7 = ml & 7;                       // == p&7 for both pt

    // ---------------- GEMM1: h1 = W0 @ x ----------------
    v4f acc1[8][2];
#pragma unroll
    for (int ot = 0; ot < 8; ++ot)
        for (int pt = 0; pt < 2; ++pt)
            acc1[ot][pt] = (v4f){0.f, 0.f, 0.f, 0.f};

#pragma unroll
    for (int s = 0; s < 12; ++s) {
        int kc = s * 4 + ql;
        int pc = (kc ^ px7) * 8;
        v8h bf0 = __builtin_bit_cast(v8h, *(const uint4*)&sx[p0 * KIN + pc]);
        v8h bf1 = __builtin_bit_cast(v8h, *(const uint4*)&sx[(p0 + 16) * KIN + pc]);
#pragma unroll
        for (int ot = 0; ot < 8; ++ot) {
            int o = wo * 128 + ot * 16 + ml;
            v8h af = __builtin_bit_cast(v8h, W0v[o * 48 + kc]);
            acc1[ot][0] = __builtin_amdgcn_mfma_f32_16x16x32_f16(af, bf0, acc1[ot][0], 0, 0, 0);
            acc1[ot][1] = __builtin_amdgcn_mfma_f32_16x16x32_f16(af, bf1, acc1[ot][1], 0, 0, 0);
        }
    }
    __syncthreads();   // all x reads done before h1 overlays sx

    // epilogue 1: BN+ReLU -> fp16 h1[p][o] (row stride 256, swizzled)
    const float* s0v = sst;
    const float* t0v = sst + 256;
#pragma unroll
    for (int ot = 0; ot < 8; ++ot) {
        int o0 = wo * 128 + ot * 16 + ql * 4;
        float sc0 = s0v[o0], sc1 = s0v[o0 + 1], sc2 = s0v[o0 + 2], sc3 = s0v[o0 + 3];
        float sh0 = t0v[o0], sh1 = t0v[o0 + 1], sh2 = t0v[o0 + 2], sh3 = t0v[o0 + 3];
        int chunk = ((o0 >> 3) ^ px7);
#pragma unroll
        for (int pt = 0; pt < 2; ++pt) {
            int p = p0 + pt * 16;
            float z0 = fmaxf(fmaf(acc1[ot][pt][0], sc0, sh0), 0.f);
            float z1 = fmaxf(fmaf(acc1[ot][pt][1], sc1, sh1), 0.f);
            float z2 = fmaxf(fmaf(acc1[ot][pt][2], sc2, sh2), 0.f);
            float z3 = fmaxf(fmaf(acc1[ot][pt][3], sc3, sh3), 0.f);
            u32 lo = f2h(z0) | ((u32)f2h(z1) << 16);
            u32 hi = f2h(z2) | ((u32)f2h(z3) << 16);
            *(uint2*)&sx[p * HID + chunk * 8 + (o0 & 7)] = make_uint2(lo, hi);
        }
    }
    __syncthreads();

    // ---------------- GEMM2: h2 = W1 @ h1 ----------------
    v4f acc2[8][2];
#pragma unroll
    for (int ot = 0; ot < 8; ++ot)
        for (int pt = 0; pt < 2; ++pt)
            acc2[ot][pt] = (v4f){0.f, 0.f, 0.f, 0.f};

#pragma unroll
    for (int s = 0; s < 8; ++s) {
        int kc = s * 4 + ql;
        int pc = (kc ^ px7) * 8;
        v8h bf0 = __builtin_bit_cast(v8h, *(const uint4*)&sx[p0 * HID + pc]);
        v8h bf1 = __builtin_bit_cast(v8h, *(const uint4*)&sx[(p0 + 16) * HID + pc]);
#pragma unroll
        for (int ot = 0; ot < 8; ++ot) {
            int o = wo * 128 + ot * 16 + ml;
            v8h af = __builtin_bit_cast(v8h, W1v[o * 32 + kc]);
            acc2[ot][0] = __builtin_amdgcn_mfma_f32_16x16x32_f16(af, bf0, acc2[ot][0], 0, 0, 0);
            acc2[ot][1] = __builtin_amdgcn_mfma_f32_16x16x32_f16(af, bf1, acc2[ot][1], 0, 0, 0);
        }
    }

    // epilogue 2: BN + ReLU (via max with 0) + channel max
    const float* s1v = sst + 512;
    const float* t1v = sst + 768;
    float mx0 = 0.f, mx1 = 0.f;   // relu floor = 0
#pragma unroll
    for (int ot = 0; ot < 8; ++ot) {
        int o0 = wo * 128 + ot * 16 + ql * 4;
#pragma unroll
        for (int r = 0; r < 4; ++r) {
            float sc = s1v[o0 + r], sh = t1v[o0 + r];
            mx0 = fmaxf(mx0, fmaf(acc2[ot][0][r], sc, sh));
            mx1 = fmaxf(mx1, fmaf(acc2[ot][1][r], sc, sh));
        }
    }
    mx0 = fmaxf(mx0, __shfl_xor(mx0, 16, 64));
    mx0 = fmaxf(mx0, __shfl_xor(mx0, 32, 64));
    mx1 = fmaxf(mx1, __shfl_xor(mx1, 16, 64));
    mx1 = fmaxf(mx1, __shfl_xor(mx1, 32, 64));
    if (lane < 16) {
        sred[wo][wp * 32 + lane]      = mx0;
        sred[wo][wp * 32 + 16 + lane] = mx1;
    }
    __syncthreads();
    if (tid < 64)
        out[(size_t)b * N1 + n0 + tid] = fmaxf(sred[0][tid], sred[1][tid]);
}

// =====================================================================
extern "C" void kernel_launch(void* const* d_in, const int* in_sizes, int n_in,
                              void* d_out, int out_size, void* d_ws, size_t ws_size,
                              hipStream_t stream)
{
    const float* xyz1     = (const float*)d_in[0];
    const float* xyz2     = (const float*)d_in[1];
    const float* points2  = (const float*)d_in[2];
    const float* points1  = (const float*)d_in[3];
    const float* pointsb1 = (const float*)d_in[4];
    const float* w0   = (const float*)d_in[5];
    const float* b0   = (const float*)d_in[6];
    const float* g0   = (const float*)d_in[7];
    const float* be0  = (const float*)d_in[8];
    const float* m0   = (const float*)d_in[9];
    const float* v0   = (const float*)d_in[10];
    const float* w1   = (const float*)d_in[11];
    const float* b1   = (const float*)d_in[12];
    const float* g1   = (const float*)d_in[13];
    const float* be1  = (const float*)d_in[14];
    const float* m1   = (const float*)d_in[15];
    const float* v1   = (const float*)d_in[16];
    float* out = (float*)d_out;

    char* ws = (char*)d_ws;
    u16*    W0h   = (u16*)(ws + 0);
    u16*    W1h   = (u16*)(ws + 196608);
    float*  sst   = (float*)(ws + 327680);
    float4* xyz2q = (float4*)(ws + 331776);
    int*    idx3  = (int*)(ws + 593920);
    float*  w3    = (float*)(ws + 1380352);
    float*  p2t   = (float*)(ws + 2166784);

    prep_kernel<<<706, 256, 0, stream>>>(w0, w1, b0, g0, be0, m0, v0,
                                         b1, g1, be1, m1, v1, xyz2,
                                         W0h, W1h, sst, xyz2q);
    transpose_kernel<<<dim3(64, 4, 4), 256, 0, stream>>>(points2, p2t);
    knn_kernel<<<dim3(256, 4), 256, 0, stream>>>(xyz1, xyz2q, idx3, w3);
    mlp_kernel<<<dim3(256, 4), 256, 0, stream>>>(points1, pointsb1,
                                                 (const float4*)p2t, idx3, w3,
                                                 (const uint4*)W0h, (const uint4*)W1h,
                                                 sst, out);
}

// Round 8
// 340.848 us; speedup vs baseline: 1.1909x; 1.0875x over previous
//
#include <hip/hip_runtime.h>

#define N1 16384
#define N2 4096
#define CC 128
#define KIN 384
#define HID 256

typedef unsigned short u16;
typedef unsigned int u32;

typedef _Float16 v8h __attribute__((ext_vector_type(8)));
typedef float v4f __attribute__((ext_vector_type(4)));

// ---------- workspace layout (bytes) ----------
// W0h  fp16 256x384           @ 0        (196608)
// W1h  fp16 256x256           @ 196608   (131072)
// sst  fp32 s0,t0,s1,t1 x256  @ 327680   (4096)
// xyz2q float4 B*N2           @ 331776   (262144)
// idx3 int B*N1*3             @ 593920   (786432)
// w3   fp32 B*N1*3            @ 1380352  (786432)
// p2t  fp32 B*N2*C            @ 2166784  (8388608)
// total = 10555392

__device__ __forceinline__ u16 f2h(float f) {
    _Float16 h = (_Float16)f;
    return __builtin_bit_cast(u16, h);
}

// =====================================================================
// Prep: convert weights to fp16, fold BN into scale/shift, build xyz2q
// =====================================================================
__global__ __launch_bounds__(256) void prep_kernel(
    const float* __restrict__ w0, const float* __restrict__ w1,
    const float* __restrict__ b0, const float* __restrict__ g0, const float* __restrict__ be0,
    const float* __restrict__ m0, const float* __restrict__ v0,
    const float* __restrict__ b1, const float* __restrict__ g1, const float* __restrict__ be1,
    const float* __restrict__ m1, const float* __restrict__ v1,
    const float* __restrict__ xyz2,
    u16* __restrict__ W0h, u16* __restrict__ W1h,
    float* __restrict__ sst, float4* __restrict__ xyz2q)
{
    int id = blockIdx.x * 256 + threadIdx.x;
    if (id < 98304) {
        W0h[id] = f2h(w0[id]);
    } else if (id < 163840) {
        int t = id - 98304;
        W1h[t] = f2h(w1[t]);
    } else if (id < 164352) {
        int t = id - 163840;
        int o = t & 255;
        if (t < 256) {
            float s = g0[o] * rsqrtf(v0[o] + 1e-5f);
            sst[o]       = s;
            sst[256 + o] = (b0[o] - m0[o]) * s + be0[o];
        } else {
            float s = g1[o] * rsqrtf(v1[o] + 1e-5f);
            sst[512 + o] = s;
            sst[768 + o] = (b1[o] - m1[o]) * s + be1[o];
        }
    } else if (id < 180736) {
        int t = id - 164352;  // b*N2+n
        float x = xyz2[(size_t)t * 3 + 0];
        float y = xyz2[(size_t)t * 3 + 1];
        float z = xyz2[(size_t)t * 3 + 2];
        xyz2q[t] = make_float4(x, y, z, fmaf(x, x, fmaf(y, y, z * z)));
    }
}

// =====================================================================
// Transpose points2 (B,C,N2) -> p2t (B,N2,C), LDS-tiled
// =====================================================================
__global__ __launch_bounds__(256) void transpose_kernel(
    const float* __restrict__ points2, float* __restrict__ p2t)
{
    __shared__ float tile[32][65];
    int n20 = blockIdx.x * 64;
    int c0  = blockIdx.y * 32;
    int b   = blockIdx.z;
    int tid = threadIdx.x;
    int n2i = tid & 63, ci = tid >> 6;
    for (int cc = ci; cc < 32; cc += 4)
        tile[cc][n2i] = points2[((size_t)b * CC + (c0 + cc)) * N2 + n20 + n2i];
    __syncthreads();
    int co = tid & 31, ro = tid >> 5;
    for (int rr = ro; rr < 64; rr += 8)
        p2t[((size_t)b * N2 + n20 + rr) * CC + c0 + co] = tile[co][rr];
}

// =====================================================================
// 3-NN + inverse-distance weights  (R7 structure -- proven, unchanged)
// =====================================================================
#define BINS(t, cand, D0, D1, D2, I0, I1, I2) do {                    \
    bool c0 = (t) < (D0);                                             \
    bool c1 = (t) < (D1);                                             \
    bool c2 = (t) < (D2);                                             \
    I2 = c1 ? (I1) : (c2 ? (cand) : (I2));   /* old I1 */             \
    I1 = c0 ? (I0) : (c1 ? (cand) : (I1));   /* old I0 */             \
    I0 = c0 ? (cand) : (I0);                                          \
    D2 = __builtin_amdgcn_fmed3f((D1), (t), (D2));  /* old D1 */      \
    D1 = __builtin_amdgcn_fmed3f((D0), (t), (D1));  /* old D0 */      \
    D0 = fminf((t), (D0));                                            \
} while (0)

#define INS3LEX(t, j, D0, D1, D2, I0, I1, I2) do {                    \
    bool lt2 = (t) < (D2) || ((t) == (D2) && (j) < (I2));             \
    bool lt1 = (t) < (D1) || ((t) == (D1) && (j) < (I1));             \
    bool lt0 = (t) < (D0) || ((t) == (D0) && (j) < (I0));             \
    if (lt2) {                                                        \
        if (lt1) {                                                    \
            D2 = (D1); I2 = (I1);                                     \
            if (lt0) { D1 = (D0); I1 = (I0); D0 = (t); I0 = (j); }    \
            else     { D1 = (t); I1 = (j); }                          \
        } else { D2 = (t); I2 = (j); }                                \
    }                                                                 \
} while (0)

#define MERGE_STEP(st, D0, D1, D2, I0, I1, I2) do {                   \
    float e0 = __shfl_xor((D0), (st), 64);                            \
    float e1 = __shfl_xor((D1), (st), 64);                            \
    float e2 = __shfl_xor((D2), (st), 64);                            \
    int   j0 = __shfl_xor((I0), (st), 64);                            \
    int   j1 = __shfl_xor((I1), (st), 64);                            \
    int   j2 = __shfl_xor((I2), (st), 64);                            \
    INS3LEX(e0, j0, D0, D1, D2, I0, I1, I2);                          \
    INS3LEX(e1, j1, D0, D1, D2, I0, I1, I2);                          \
    INS3LEX(e2, j2, D0, D1, D2, I0, I1, I2);                          \
} while (0)

#define KNN_OUT(Q, D0, D1, D2, I0, I1, I2, PP) do {                   \
    float r0 = 1.f / ((D0) + (PP));                                   \
    float r1 = 1.f / ((D1) + (PP));                                   \
    float r2 = 1.f / ((D2) + (PP));                                   \
    float inv = 1.f / (r0 + r1 + r2);                                 \
    size_t o3 = ((size_t)b * N1 + p0 + (Q)) * 3;                      \
    idx3[o3]     = (I0);                                              \
    idx3[o3 + 1] = (I1);                                              \
    idx3[o3 + 2] = (I2);                                              \
    w3[o3]     = r0 * inv;                                            \
    w3[o3 + 1] = r1 * inv;                                            \
    w3[o3 + 2] = r2 * inv;                                            \
} while (0)

__global__ __launch_bounds__(256)
__attribute__((amdgpu_waves_per_eu(4, 4)))
void knn_kernel(
    const float* __restrict__ xyz1, const float4* __restrict__ xyz2q,
    int* __restrict__ idx3, float* __restrict__ w3)
{
    __shared__ float4 slds[2048];   // 32768 B

    int tid = threadIdx.x;
    int b   = blockIdx.y;
    int n0  = blockIdx.x * 64;

    int s  = tid & 15;      // candidate split (lane bits 0..3)
    int g  = tid >> 4;      // query group 0..15
    int p0 = n0 + g * 4;

    size_t pb = ((size_t)b * N1 + p0) * 3;
    float x0 = xyz1[pb + 0],  y0 = xyz1[pb + 1],  z0 = xyz1[pb + 2];
    float x1 = xyz1[pb + 3],  y1 = xyz1[pb + 4],  z1 = xyz1[pb + 5];
    float x2 = xyz1[pb + 6],  y2 = xyz1[pb + 7],  z2 = xyz1[pb + 8];
    float x3 = xyz1[pb + 9],  y3 = xyz1[pb + 10], z3 = xyz1[pb + 11];
    float ax0 = -2.f * x0, ay0 = -2.f * y0, az0 = -2.f * z0;
    float ax1 = -2.f * x1, ay1 = -2.f * y1, az1 = -2.f * z1;
    float ax2 = -2.f * x2, ay2 = -2.f * y2, az2 = -2.f * z2;
    float ax3 = -2.f * x3, ay3 = -2.f * y3, az3 = -2.f * z3;
    float pp0 = fmaf(x0, x0, fmaf(y0, y0, z0 * z0));
    float pp1 = fmaf(x1, x1, fmaf(y1, y1, z1 * z1));
    float pp2 = fmaf(x2, x2, fmaf(y2, y2, z2 * z2));
    float pp3 = fmaf(x3, x3, fmaf(y3, y3, z3 * z3));

    float da0 = 1e30f, da1 = 1e30f, da2 = 1e30f;
    float db0 = 1e30f, db1 = 1e30f, db2 = 1e30f;
    float dc0 = 1e30f, dc1 = 1e30f, dc2 = 1e30f;
    float dd0 = 1e30f, dd1 = 1e30f, dd2 = 1e30f;
    int   ia0 = 0, ia1 = 0, ia2 = 0;
    int   ib0 = 0, ib1 = 0, ib2 = 0;
    int   ic0 = 0, ic1 = 0, ic2 = 0;
    int   id0 = 0, id1 = 0, id2 = 0;

#pragma unroll
    for (int stage = 0; stage < 2; ++stage) {
        int base = stage * 2048;
        for (int i = tid; i < 2048; i += 256)
            slds[i] = xyz2q[(size_t)b * N2 + base + i];
        __syncthreads();

#pragma unroll 4
        for (int k = 0; k < 2048 / 16; ++k) {
            int c = s + (k << 4);
            float4 v = slds[c];
            int cand = base + c;
            float t0 = fmaf(ax0, v.x, fmaf(ay0, v.y, fmaf(az0, v.z, v.w)));
            float t1 = fmaf(ax1, v.x, fmaf(ay1, v.y, fmaf(az1, v.z, v.w)));
            float t2 = fmaf(ax2, v.x, fmaf(ay2, v.y, fmaf(az2, v.z, v.w)));
            float t3 = fmaf(ax3, v.x, fmaf(ay3, v.y, fmaf(az3, v.z, v.w)));
            BINS(t0, cand, da0, da1, da2, ia0, ia1, ia2);
            BINS(t1, cand, db0, db1, db2, ib0, ib1, ib2);
            BINS(t2, cand, dc0, dc1, dc2, ic0, ic1, ic2);
            BINS(t3, cand, dd0, dd1, dd2, id0, id1, id2);
        }
        __syncthreads();
    }

#pragma unroll
    for (int st = 1; st <= 8; st <<= 1) {
        MERGE_STEP(st, da0, da1, da2, ia0, ia1, ia2);
        MERGE_STEP(st, db0, db1, db2, ib0, ib1, ib2);
        MERGE_STEP(st, dc0, dc1, dc2, ic0, ic1, ic2);
        MERGE_STEP(st, dd0, dd1, dd2, id0, id1, id2);
    }

    if (s == 0) {
        KNN_OUT(0, da0, da1, da2, ia0, ia1, ia2, pp0);
        KNN_OUT(1, db0, db1, db2, ib0, ib1, ib2, pp1);
        KNN_OUT(2, dc0, dc1, dc2, ic0, ic1, ic2, pp2);
        KNN_OUT(3, dd0, dd1, dd2, id0, id1, id2, pp3);
    }
}

// =====================================================================
// Fused interpolate + concat + MLP(384->256->256, BN+ReLU) + channel max
// block = 256 thr (4 waves, 2x2 over o/p), 64 points per block.
// Staging is bulk-issued (R7 evidence: rolled staging serialized ~24
// memory round trips -> MfmaUtil 5.6%, all pipes idle).
// waves_per_eu(3,3): 3 blocks/CU (LDS 49.7KB), ~170 VGPR budget.
// =====================================================================
__global__ __launch_bounds__(256)
__attribute__((amdgpu_waves_per_eu(3, 3)))
void mlp_kernel(
    const float* __restrict__ points1, const float* __restrict__ pointsb1,
    const float4* __restrict__ p2t4,
    const int* __restrict__ idx3, const float* __restrict__ w3,
    const uint4* __restrict__ W0v, const uint4* __restrict__ W1v,
    const float* __restrict__ sst, float* __restrict__ out)
{
    // x: 64 rows x 384 fp16, 16B-chunk swizzled by (p&7); h1 overlays (64x256)
    __shared__ __align__(16) u16 sx[64 * KIN];   // 49152 B
    __shared__ float sred[2][64];
    __shared__ int   s_idx[192];
    __shared__ float s_w[192];

    int tid = threadIdx.x;
    int b   = blockIdx.y;
    int n0  = blockIdx.x * 64;

    // ---- phase 0: issue neighbor idx/w loads (oldest in flight) ----
    int   jidx = 0; float jw = 0.f;
    if (tid < 192) {
        size_t gi = ((size_t)b * N1 + n0) * 3 + tid;
        jidx = idx3[gi];
        jw   = w3[gi];
    }

    // ---- phase 1: bulk-issue ALL points1/points_b1 loads ----
    int pL = tid & 63;
    int t4 = (tid >> 6) * 4;
    float av1[8][4], av2[8][4];
#pragma unroll
    for (int k = 0; k < 8; ++k) {
        int r4 = t4 + 16 * k;
        size_t base = ((size_t)b * CC + r4) * N1 + n0 + pL;
        av1[k][0] = points1[base];
        av1[k][1] = points1[base + (size_t)N1];
        av1[k][2] = points1[base + (size_t)2 * N1];
        av1[k][3] = points1[base + (size_t)3 * N1];
    }
#pragma unroll
    for (int k = 0; k < 8; ++k) {
        int r4 = t4 + 16 * k;
        size_t base = ((size_t)b * CC + r4) * N1 + n0 + pL;
        av2[k][0] = pointsb1[base];
        av2[k][1] = pointsb1[base + (size_t)N1];
        av2[k][2] = pointsb1[base + (size_t)2 * N1];
        av2[k][3] = pointsb1[base + (size_t)3 * N1];
    }

    // ---- phase 2: publish idx/w, barrier ----
    if (tid < 192) {
        s_idx[tid] = jidx;
        s_w[tid]   = jw;
    }
    __syncthreads();

    // ---- phase 3: convert + write staged rows (loads already landed) ----
#pragma unroll
    for (int k = 0; k < 8; ++k) {
        int r4 = t4 + 16 * k;
        u32 lo = f2h(av1[k][0]) | ((u32)f2h(av1[k][1]) << 16);
        u32 hi = f2h(av1[k][2]) | ((u32)f2h(av1[k][3]) << 16);
        int chunk = (r4 >> 3) ^ (pL & 7);
        *(uint2*)&sx[pL * KIN + chunk * 8 + (r4 & 7)] = make_uint2(lo, hi);
    }
#pragma unroll
    for (int k = 0; k < 8; ++k) {
        int k4 = 256 + t4 + 16 * k;
        u32 lo = f2h(av2[k][0]) | ((u32)f2h(av2[k][1]) << 16);
        u32 hi = f2h(av2[k][2]) | ((u32)f2h(av2[k][3]) << 16);
        int chunk = (k4 >> 3) ^ (pL & 7);
        *(uint2*)&sx[pL * KIN + chunk * 8 + (k4 & 7)] = make_uint2(lo, hi);
    }

    // ---- phase 4: gather + interpolate, 2 chunks of 4 rows ----
    int c4 = tid & 31;
    int g0 = tid >> 5;
    int k4g = 128 + c4 * 4;
#pragma unroll
    for (int h = 0; h < 2; ++h) {
        float4 f0[4], f1[4], f2[4];
        float w0a[4], w1a[4], w2a[4];
#pragma unroll
        for (int k = 0; k < 4; ++k) {
            int p = g0 + (h * 4 + k) * 8;
            int j0 = s_idx[p * 3 + 0], j1 = s_idx[p * 3 + 1], j2 = s_idx[p * 3 + 2];
            w0a[k] = s_w[p * 3 + 0]; w1a[k] = s_w[p * 3 + 1]; w2a[k] = s_w[p * 3 + 2];
            f0[k] = p2t4[((size_t)b * N2 + j0) * 32 + c4];
            f1[k] = p2t4[((size_t)b * N2 + j1) * 32 + c4];
            f2[k] = p2t4[((size_t)b * N2 + j2) * 32 + c4];
        }
#pragma unroll
        for (int k = 0; k < 4; ++k) {
            int p = g0 + (h * 4 + k) * 8;
            float e0 = fmaf(w0a[k], f0[k].x, fmaf(w1a[k], f1[k].x, w2a[k] * f2[k].x));
            float e1 = fmaf(w0a[k], f0[k].y, fmaf(w1a[k], f1[k].y, w2a[k] * f2[k].y));
            float e2 = fmaf(w0a[k], f0[k].z, fmaf(w1a[k], f1[k].z, w2a[k] * f2[k].z));
            float e3 = fmaf(w0a[k], f0[k].w, fmaf(w1a[k], f1[k].w, w2a[k] * f2[k].w));
            u32 lo = f2h(e0) | ((u32)f2h(e1) << 16);
            u32 hi = f2h(e2) | ((u32)f2h(e3) << 16);
            int chunk = (k4g >> 3) ^ (p & 7);
            *(uint2*)&sx[p * KIN + chunk * 8 + (k4g & 7)] = make_uint2(lo, hi);
        }
    }
    __syncthreads();

    int lane = tid & 63, wave = tid >> 6;
    int wo = wave >> 1, wp = wave & 1;      // o-half, p-half
    int ml = lane & 15, ql = lane >> 4;     // frag row/col, quad
    int p0  = wp * 32 + ml;                 // p for pt=0 (pt=1: +16)
    int px7 = ml & 7;                       // == p&7 for both pt

    // ---------------- GEMM1: h1 = W0 @ x ----------------
    v4f acc1[8][2];
#pragma unroll
    for (int ot = 0; ot < 8; ++ot)
        for (int pt = 0; pt < 2; ++pt)
            acc1[ot][pt] = (v4f){0.f, 0.f, 0.f, 0.f};

#pragma unroll
    for (int s = 0; s < 12; ++s) {
        int kc = s * 4 + ql;
        int pc = (kc ^ px7) * 8;
        v8h bf0 = __builtin_bit_cast(v8h, *(const uint4*)&sx[p0 * KIN + pc]);
        v8h bf1 = __builtin_bit_cast(v8h, *(const uint4*)&sx[(p0 + 16) * KIN + pc]);
#pragma unroll
        for (int ot = 0; ot < 8; ++ot) {
            int o = wo * 128 + ot * 16 + ml;
            v8h af = __builtin_bit_cast(v8h, W0v[o * 48 + kc]);
            acc1[ot][0] = __builtin_amdgcn_mfma_f32_16x16x32_f16(af, bf0, acc1[ot][0], 0, 0, 0);
            acc1[ot][1] = __builtin_amdgcn_mfma_f32_16x16x32_f16(af, bf1, acc1[ot][1], 0, 0, 0);
        }
    }
    __syncthreads();   // all x reads done before h1 overlays sx

    // epilogue 1: BN+ReLU -> fp16 h1[p][o] (row stride 256, swizzled)
    const float* s0v = sst;
    const float* t0v = sst + 256;
#pragma unroll
    for (int ot = 0; ot < 8; ++ot) {
        int o0 = wo * 128 + ot * 16 + ql * 4;
        float sc0 = s0v[o0], sc1 = s0v[o0 + 1], sc2 = s0v[o0 + 2], sc3 = s0v[o0 + 3];
        float sh0 = t0v[o0], sh1 = t0v[o0 + 1], sh2 = t0v[o0 + 2], sh3 = t0v[o0 + 3];
        int chunk = ((o0 >> 3) ^ px7);
#pragma unroll
        for (int pt = 0; pt < 2; ++pt) {
            int p = p0 + pt * 16;
            float z0 = fmaxf(fmaf(acc1[ot][pt][0], sc0, sh0), 0.f);
            float z1 = fmaxf(fmaf(acc1[ot][pt][1], sc1, sh1), 0.f);
            float z2 = fmaxf(fmaf(acc1[ot][pt][2], sc2, sh2), 0.f);
            float z3 = fmaxf(fmaf(acc1[ot][pt][3], sc3, sh3), 0.f);
            u32 lo = f2h(z0) | ((u32)f2h(z1) << 16);
            u32 hi = f2h(z2) | ((u32)f2h(z3) << 16);
            *(uint2*)&sx[p * HID + chunk * 8 + (o0 & 7)] = make_uint2(lo, hi);
        }
    }
    __syncthreads();

    // ---------------- GEMM2: h2 = W1 @ h1 ----------------
    v4f acc2[8][2];
#pragma unroll
    for (int ot = 0; ot < 8; ++ot)
        for (int pt = 0; pt < 2; ++pt)
            acc2[ot][pt] = (v4f){0.f, 0.f, 0.f, 0.f};

#pragma unroll
    for (int s = 0; s < 8; ++s) {
        int kc = s * 4 + ql;
        int pc = (kc ^ px7) * 8;
        v8h bf0 = __builtin_bit_cast(v8h, *(const uint4*)&sx[p0 * HID + pc]);
        v8h bf1 = __builtin_bit_cast(v8h, *(const uint4*)&sx[(p0 + 16) * HID + pc]);
#pragma unroll
        for (int ot = 0; ot < 8; ++ot) {
            int o = wo * 128 + ot * 16 + ml;
            v8h af = __builtin_bit_cast(v8h, W1v[o * 32 + kc]);
            acc2[ot][0] = __builtin_amdgcn_mfma_f32_16x16x32_f16(af, bf0, acc2[ot][0], 0, 0, 0);
            acc2[ot][1] = __builtin_amdgcn_mfma_f32_16x16x32_f16(af, bf1, acc2[ot][1], 0, 0, 0);
        }
    }

    // epilogue 2: BN + ReLU (via max with 0) + channel max
    const float* s1v = sst + 512;
    const float* t1v = sst + 768;
    float mx0 = 0.f, mx1 = 0.f;   // relu floor = 0
#pragma unroll
    for (int ot = 0; ot < 8; ++ot) {
        int o0 = wo * 128 + ot * 16 + ql * 4;
#pragma unroll
        for (int r = 0; r < 4; ++r) {
            float sc = s1v[o0 + r], sh = t1v[o0 + r];
            mx0 = fmaxf(mx0, fmaf(acc2[ot][0][r], sc, sh));
            mx1 = fmaxf(mx1, fmaf(acc2[ot][1][r], sc, sh));
        }
    }
    mx0 = fmaxf(mx0, __shfl_xor(mx0, 16, 64));
    mx0 = fmaxf(mx0, __shfl_xor(mx0, 32, 64));
    mx1 = fmaxf(mx1, __shfl_xor(mx1, 16, 64));
    mx1 = fmaxf(mx1, __shfl_xor(mx1, 32, 64));
    if (lane < 16) {
        sred[wo][wp * 32 + lane]      = mx0;
        sred[wo][wp * 32 + 16 + lane] = mx1;
    }
    __syncthreads();
    if (tid < 64)
        out[(size_t)b * N1 + n0 + tid] = fmaxf(sred[0][tid], sred[1][tid]);
}

// =====================================================================
extern "C" void kernel_launch(void* const* d_in, const int* in_sizes, int n_in,
                              void* d_out, int out_size, void* d_ws, size_t ws_size,
                              hipStream_t stream)
{
    const float* xyz1     = (const float*)d_in[0];
    const float* xyz2     = (const float*)d_in[1];
    const float* points2  = (const float*)d_in[2];
    const float* points1  = (const float*)d_in[3];
    const float* pointsb1 = (const float*)d_in[4];
    const float* w0   = (const float*)d_in[5];
    const float* b0   = (const float*)d_in[6];
    const float* g0   = (const float*)d_in[7];
    const float* be0  = (const float*)d_in[8];
    const float* m0   = (const float*)d_in[9];
    const float* v0   = (const float*)d_in[10];
    const float* w1   = (const float*)d_in[11];
    const float* b1   = (const float*)d_in[12];
    const float* g1   = (const float*)d_in[13];
    const float* be1  = (const float*)d_in[14];
    const float* m1   = (const float*)d_in[15];
    const float* v1   = (const float*)d_in[16];
    float* out = (float*)d_out;

    char* ws = (char*)d_ws;
    u16*    W0h   = (u16*)(ws + 0);
    u16*    W1h   = (u16*)(ws + 196608);
    float*  sst   = (float*)(ws + 327680);
    float4* xyz2q = (float4*)(ws + 331776);
    int*    idx3  = (int*)(ws + 593920);
    float*  w3    = (float*)(ws + 1380352);
    float*  p2t   = (float*)(ws + 2166784);

    prep_kernel<<<706, 256, 0, stream>>>(w0, w1, b0, g0, be0, m0, v0,
                                         b1, g1, be1, m1, v1, xyz2,
                                         W0h, W1h, sst, xyz2q);
    transpose_kernel<<<dim3(64, 4, 4), 256, 0, stream>>>(points2, p2t);
    knn_kernel<<<dim3(256, 4), 256, 0, stream>>>(xyz1, xyz2q, idx3, w3);
    mlp_kernel<<<dim3(256, 4), 256, 0, stream>>>(points1, pointsb1,
                                                 (const float4*)p2t, idx3, w3,
                                                 (const uint4*)W0h, (const uint4*)W1h,
                                                 sst, out);
}

// Round 9
// 327.444 us; speedup vs baseline: 1.2396x; 1.0409x over previous
//
#include <hip/hip_runtime.h>

#define N1 16384
#define N2 4096
#define CC 128
#define KIN 384
#define HID 256

typedef unsigned short u16;
typedef unsigned int u32;

typedef _Float16 v8h __attribute__((ext_vector_type(8)));
typedef float v4f __attribute__((ext_vector_type(4)));

// ---------- workspace layout (bytes) ----------
// W0h  fp16 256x384           @ 0        (196608)
// W1h  fp16 256x256           @ 196608   (131072)
// sst  fp32 s0,t0,s1,t1 x256  @ 327680   (4096)
// xyz2q float4 B*N2           @ 331776   (262144)
// idx3 int B*N1*3             @ 593920   (786432)
// w3   fp32 B*N1*3            @ 1380352  (786432)
// p2t  fp32 B*N2*C            @ 2166784  (8388608)
// total = 10555392

__device__ __forceinline__ u16 f2h(float f) {
    _Float16 h = (_Float16)f;
    return __builtin_bit_cast(u16, h);
}

// =====================================================================
// Prep: convert weights to fp16, fold BN into scale/shift, build xyz2q
// =====================================================================
__global__ __launch_bounds__(256) void prep_kernel(
    const float* __restrict__ w0, const float* __restrict__ w1,
    const float* __restrict__ b0, const float* __restrict__ g0, const float* __restrict__ be0,
    const float* __restrict__ m0, const float* __restrict__ v0,
    const float* __restrict__ b1, const float* __restrict__ g1, const float* __restrict__ be1,
    const float* __restrict__ m1, const float* __restrict__ v1,
    const float* __restrict__ xyz2,
    u16* __restrict__ W0h, u16* __restrict__ W1h,
    float* __restrict__ sst, float4* __restrict__ xyz2q)
{
    int id = blockIdx.x * 256 + threadIdx.x;
    if (id < 98304) {
        W0h[id] = f2h(w0[id]);
    } else if (id < 163840) {
        int t = id - 98304;
        W1h[t] = f2h(w1[t]);
    } else if (id < 164352) {
        int t = id - 163840;
        int o = t & 255;
        if (t < 256) {
            float s = g0[o] * rsqrtf(v0[o] + 1e-5f);
            sst[o]       = s;
            sst[256 + o] = (b0[o] - m0[o]) * s + be0[o];
        } else {
            float s = g1[o] * rsqrtf(v1[o] + 1e-5f);
            sst[512 + o] = s;
            sst[768 + o] = (b1[o] - m1[o]) * s + be1[o];
        }
    } else if (id < 180736) {
        int t = id - 164352;  // b*N2+n
        float x = xyz2[(size_t)t * 3 + 0];
        float y = xyz2[(size_t)t * 3 + 1];
        float z = xyz2[(size_t)t * 3 + 2];
        xyz2q[t] = make_float4(x, y, z, fmaf(x, x, fmaf(y, y, z * z)));
    }
}

// =====================================================================
// Transpose points2 (B,C,N2) -> p2t (B,N2,C), LDS-tiled
// =====================================================================
__global__ __launch_bounds__(256) void transpose_kernel(
    const float* __restrict__ points2, float* __restrict__ p2t)
{
    __shared__ float tile[32][65];
    int n20 = blockIdx.x * 64;
    int c0  = blockIdx.y * 32;
    int b   = blockIdx.z;
    int tid = threadIdx.x;
    int n2i = tid & 63, ci = tid >> 6;
    for (int cc = ci; cc < 32; cc += 4)
        tile[cc][n2i] = points2[((size_t)b * CC + (c0 + cc)) * N2 + n20 + n2i];
    __syncthreads();
    int co = tid & 31, ro = tid >> 5;
    for (int rr = ro; rr < 64; rr += 8)
        p2t[((size_t)b * N2 + n20 + rr) * CC + c0 + co] = tile[co][rr];
}

// =====================================================================
// 3-NN + inverse-distance weights  (R7 structure -- proven, unchanged)
// =====================================================================
#define BINS(t, cand, D0, D1, D2, I0, I1, I2) do {                    \
    bool c0 = (t) < (D0);                                             \
    bool c1 = (t) < (D1);                                             \
    bool c2 = (t) < (D2);                                             \
    I2 = c1 ? (I1) : (c2 ? (cand) : (I2));   /* old I1 */             \
    I1 = c0 ? (I0) : (c1 ? (cand) : (I1));   /* old I0 */             \
    I0 = c0 ? (cand) : (I0);                                          \
    D2 = __builtin_amdgcn_fmed3f((D1), (t), (D2));  /* old D1 */      \
    D1 = __builtin_amdgcn_fmed3f((D0), (t), (D1));  /* old D0 */      \
    D0 = fminf((t), (D0));                                            \
} while (0)

#define INS3LEX(t, j, D0, D1, D2, I0, I1, I2) do {                    \
    bool lt2 = (t) < (D2) || ((t) == (D2) && (j) < (I2));             \
    bool lt1 = (t) < (D1) || ((t) == (D1) && (j) < (I1));             \
    bool lt0 = (t) < (D0) || ((t) == (D0) && (j) < (I0));             \
    if (lt2) {                                                        \
        if (lt1) {                                                    \
            D2 = (D1); I2 = (I1);                                     \
            if (lt0) { D1 = (D0); I1 = (I0); D0 = (t); I0 = (j); }    \
            else     { D1 = (t); I1 = (j); }                          \
        } else { D2 = (t); I2 = (j); }                                \
    }                                                                 \
} while (0)

#define MERGE_STEP(st, D0, D1, D2, I0, I1, I2) do {                   \
    float e0 = __shfl_xor((D0), (st), 64);                            \
    float e1 = __shfl_xor((D1), (st), 64);                            \
    float e2 = __shfl_xor((D2), (st), 64);                            \
    int   j0 = __shfl_xor((I0), (st), 64);                            \
    int   j1 = __shfl_xor((I1), (st), 64);                            \
    int   j2 = __shfl_xor((I2), (st), 64);                            \
    INS3LEX(e0, j0, D0, D1, D2, I0, I1, I2);                          \
    INS3LEX(e1, j1, D0, D1, D2, I0, I1, I2);                          \
    INS3LEX(e2, j2, D0, D1, D2, I0, I1, I2);                          \
} while (0)

#define KNN_OUT(Q, D0, D1, D2, I0, I1, I2, PP) do {                   \
    float r0 = 1.f / ((D0) + (PP));                                   \
    float r1 = 1.f / ((D1) + (PP));                                   \
    float r2 = 1.f / ((D2) + (PP));                                   \
    float inv = 1.f / (r0 + r1 + r2);                                 \
    size_t o3 = ((size_t)b * N1 + p0 + (Q)) * 3;                      \
    idx3[o3]     = (I0);                                              \
    idx3[o3 + 1] = (I1);                                              \
    idx3[o3 + 2] = (I2);                                              \
    w3[o3]     = r0 * inv;                                            \
    w3[o3 + 1] = r1 * inv;                                            \
    w3[o3 + 2] = r2 * inv;                                            \
} while (0)

__global__ __launch_bounds__(256)
__attribute__((amdgpu_waves_per_eu(4, 4)))
void knn_kernel(
    const float* __restrict__ xyz1, const float4* __restrict__ xyz2q,
    int* __restrict__ idx3, float* __restrict__ w3)
{
    __shared__ float4 slds[2048];   // 32768 B

    int tid = threadIdx.x;
    int b   = blockIdx.y;
    int n0  = blockIdx.x * 64;

    int s  = tid & 15;      // candidate split (lane bits 0..3)
    int g  = tid >> 4;      // query group 0..15
    int p0 = n0 + g * 4;

    size_t pb = ((size_t)b * N1 + p0) * 3;
    float x0 = xyz1[pb + 0],  y0 = xyz1[pb + 1],  z0 = xyz1[pb + 2];
    float x1 = xyz1[pb + 3],  y1 = xyz1[pb + 4],  z1 = xyz1[pb + 5];
    float x2 = xyz1[pb + 6],  y2 = xyz1[pb + 7],  z2 = xyz1[pb + 8];
    float x3 = xyz1[pb + 9],  y3 = xyz1[pb + 10], z3 = xyz1[pb + 11];
    float ax0 = -2.f * x0, ay0 = -2.f * y0, az0 = -2.f * z0;
    float ax1 = -2.f * x1, ay1 = -2.f * y1, az1 = -2.f * z1;
    float ax2 = -2.f * x2, ay2 = -2.f * y2, az2 = -2.f * z2;
    float ax3 = -2.f * x3, ay3 = -2.f * y3, az3 = -2.f * z3;
    float pp0 = fmaf(x0, x0, fmaf(y0, y0, z0 * z0));
    float pp1 = fmaf(x1, x1, fmaf(y1, y1, z1 * z1));
    float pp2 = fmaf(x2, x2, fmaf(y2, y2, z2 * z2));
    float pp3 = fmaf(x3, x3, fmaf(y3, y3, z3 * z3));

    float da0 = 1e30f, da1 = 1e30f, da2 = 1e30f;
    float db0 = 1e30f, db1 = 1e30f, db2 = 1e30f;
    float dc0 = 1e30f, dc1 = 1e30f, dc2 = 1e30f;
    float dd0 = 1e30f, dd1 = 1e30f, dd2 = 1e30f;
    int   ia0 = 0, ia1 = 0, ia2 = 0;
    int   ib0 = 0, ib1 = 0, ib2 = 0;
    int   ic0 = 0, ic1 = 0, ic2 = 0;
    int   id0 = 0, id1 = 0, id2 = 0;

#pragma unroll
    for (int stage = 0; stage < 2; ++stage) {
        int base = stage * 2048;
        for (int i = tid; i < 2048; i += 256)
            slds[i] = xyz2q[(size_t)b * N2 + base + i];
        __syncthreads();

#pragma unroll 4
        for (int k = 0; k < 2048 / 16; ++k) {
            int c = s + (k << 4);
            float4 v = slds[c];
            int cand = base + c;
            float t0 = fmaf(ax0, v.x, fmaf(ay0, v.y, fmaf(az0, v.z, v.w)));
            float t1 = fmaf(ax1, v.x, fmaf(ay1, v.y, fmaf(az1, v.z, v.w)));
            float t2 = fmaf(ax2, v.x, fmaf(ay2, v.y, fmaf(az2, v.z, v.w)));
            float t3 = fmaf(ax3, v.x, fmaf(ay3, v.y, fmaf(az3, v.z, v.w)));
            BINS(t0, cand, da0, da1, da2, ia0, ia1, ia2);
            BINS(t1, cand, db0, db1, db2, ib0, ib1, ib2);
            BINS(t2, cand, dc0, dc1, dc2, ic0, ic1, ic2);
            BINS(t3, cand, dd0, dd1, dd2, id0, id1, id2);
        }
        __syncthreads();
    }

#pragma unroll
    for (int st = 1; st <= 8; st <<= 1) {
        MERGE_STEP(st, da0, da1, da2, ia0, ia1, ia2);
        MERGE_STEP(st, db0, db1, db2, ib0, ib1, ib2);
        MERGE_STEP(st, dc0, dc1, dc2, ic0, ic1, ic2);
        MERGE_STEP(st, dd0, dd1, dd2, id0, id1, id2);
    }

    if (s == 0) {
        KNN_OUT(0, da0, da1, da2, ia0, ia1, ia2, pp0);
        KNN_OUT(1, db0, db1, db2, ib0, ib1, ib2, pp1);
        KNN_OUT(2, dc0, dc1, dc2, ic0, ic1, ic2, pp2);
        KNN_OUT(3, dd0, dd1, dd2, id0, id1, id2, pp3);
    }
}

// =====================================================================
// Fused interpolate + concat + MLP(384->256->256, BN+ReLU) + channel max
// 32-POINT TILE: sx = 32x384 fp16 = 24.6 KB -> 5 blocks/CU at
// waves_per_eu(5,5) (20 waves/CU, 62%). R8 evidence: per-wave ILP
// staging is register-infeasible (72 VGPR), so hide latency with TLP.
// Each wave: 64 o-channels x 32 points (acc[4][2] = 32 VGPRs).
// =====================================================================
__global__ __launch_bounds__(256)
__attribute__((amdgpu_waves_per_eu(5, 5)))
void mlp_kernel(
    const float* __restrict__ points1, const float* __restrict__ pointsb1,
    const float4* __restrict__ p2t4,
    const int* __restrict__ idx3, const float* __restrict__ w3,
    const uint4* __restrict__ W0v, const uint4* __restrict__ W1v,
    const float* __restrict__ sst, float* __restrict__ out)
{
    // x: 32 rows x 384 fp16, 16B-chunk swizzled by (p&7); h1 overlays (32x256)
    __shared__ __align__(16) u16 sx[32 * KIN];   // 24576 B
    __shared__ float sred[4][32];
    __shared__ int   s_idx[96];
    __shared__ float s_w[96];

    int tid = threadIdx.x;
    int b   = blockIdx.y;
    int n0  = blockIdx.x * 32;

    if (tid < 96) {
        size_t gi = ((size_t)b * N1 + n0) * 3 + tid;
        s_idx[tid] = idx3[gi];
        s_w[tid]   = w3[gi];
    }

    // ---- stage x rows 0..127 (points1) + 256..383 (points_b1) ----
    int pL = tid & 31;
    int t4 = (tid >> 5) * 4;          // 0,4,...,28
#pragma unroll
    for (int k = 0; k < 4; ++k) {
        int r4 = t4 + 32 * k;
        size_t base = ((size_t)b * CC + r4) * N1 + n0 + pL;
        float a0 = points1[base];
        float a1 = points1[base + (size_t)N1];
        float a2 = points1[base + (size_t)2 * N1];
        float a3 = points1[base + (size_t)3 * N1];
        u32 lo = f2h(a0) | ((u32)f2h(a1) << 16);
        u32 hi = f2h(a2) | ((u32)f2h(a3) << 16);
        int chunk = (r4 >> 3) ^ (pL & 7);
        *(uint2*)&sx[pL * KIN + chunk * 8 + (r4 & 7)] = make_uint2(lo, hi);
    }
#pragma unroll
    for (int k = 0; k < 4; ++k) {
        int r4 = t4 + 32 * k;
        int k4 = 256 + r4;
        size_t base = ((size_t)b * CC + r4) * N1 + n0 + pL;
        float a0 = pointsb1[base];
        float a1 = pointsb1[base + (size_t)N1];
        float a2 = pointsb1[base + (size_t)2 * N1];
        float a3 = pointsb1[base + (size_t)3 * N1];
        u32 lo = f2h(a0) | ((u32)f2h(a1) << 16);
        u32 hi = f2h(a2) | ((u32)f2h(a3) << 16);
        int chunk = (k4 >> 3) ^ (pL & 7);
        *(uint2*)&sx[pL * KIN + chunk * 8 + (k4 & 7)] = make_uint2(lo, hi);
    }
    __syncthreads();   // s_idx/s_w visible for gather

    // ---- stage x rows 128..255: 3-NN interpolation from p2t rows ----
    int c4  = tid & 31;
    int pg  = tid >> 5;
    int k4g = 128 + c4 * 4;
#pragma unroll
    for (int k = 0; k < 4; ++k) {
        int p = pg + 8 * k;
        float w0w = s_w[p * 3 + 0], w1w = s_w[p * 3 + 1], w2w = s_w[p * 3 + 2];
        float4 f0 = p2t4[((size_t)b * N2 + s_idx[p * 3 + 0]) * 32 + c4];
        float4 f1 = p2t4[((size_t)b * N2 + s_idx[p * 3 + 1]) * 32 + c4];
        float4 f2 = p2t4[((size_t)b * N2 + s_idx[p * 3 + 2]) * 32 + c4];
        float e0 = fmaf(w0w, f0.x, fmaf(w1w, f1.x, w2w * f2.x));
        float e1 = fmaf(w0w, f0.y, fmaf(w1w, f1.y, w2w * f2.y));
        float e2 = fmaf(w0w, f0.z, fmaf(w1w, f1.z, w2w * f2.z));
        float e3 = fmaf(w0w, f0.w, fmaf(w1w, f1.w, w2w * f2.w));
        u32 lo = f2h(e0) | ((u32)f2h(e1) << 16);
        u32 hi = f2h(e2) | ((u32)f2h(e3) << 16);
        int chunk = (k4g >> 3) ^ (p & 7);
        *(uint2*)&sx[p * KIN + chunk * 8 + (k4g & 7)] = make_uint2(lo, hi);
    }
    __syncthreads();

    int lane = tid & 63, w = tid >> 6;      // wave w: o in [w*64, w*64+64)
    int ml = lane & 15, ql = lane >> 4;     // frag row/col, quad
    int px7 = ml & 7;                       // == p&7 for both pt (p=pt*16+ml)

    // ---------------- GEMM1: h1 = W0 @ x ----------------
    v4f acc1[4][2];
#pragma unroll
    for (int ot = 0; ot < 4; ++ot)
        for (int pt = 0; pt < 2; ++pt)
            acc1[ot][pt] = (v4f){0.f, 0.f, 0.f, 0.f};

#pragma unroll
    for (int s = 0; s < 12; ++s) {
        int kc = s * 4 + ql;
        int pc = (kc ^ px7) * 8;
        v8h bf0 = __builtin_bit_cast(v8h, *(const uint4*)&sx[ml * KIN + pc]);
        v8h bf1 = __builtin_bit_cast(v8h, *(const uint4*)&sx[(16 + ml) * KIN + pc]);
#pragma unroll
        for (int ot = 0; ot < 4; ++ot) {
            int o = w * 64 + ot * 16 + ml;
            v8h af = __builtin_bit_cast(v8h, W0v[o * 48 + kc]);
            acc1[ot][0] = __builtin_amdgcn_mfma_f32_16x16x32_f16(af, bf0, acc1[ot][0], 0, 0, 0);
            acc1[ot][1] = __builtin_amdgcn_mfma_f32_16x16x32_f16(af, bf1, acc1[ot][1], 0, 0, 0);
        }
    }
    __syncthreads();   // all x reads done before h1 overlays sx

    // epilogue 1: BN+ReLU -> fp16 h1[p][o] (row stride 256, swizzled)
    const float* s0v = sst;
    const float* t0v = sst + 256;
#pragma unroll
    for (int ot = 0; ot < 4; ++ot) {
        int o0 = w * 64 + ot * 16 + ql * 4;
        float sc0 = s0v[o0], sc1 = s0v[o0 + 1], sc2 = s0v[o0 + 2], sc3 = s0v[o0 + 3];
        float sh0 = t0v[o0], sh1 = t0v[o0 + 1], sh2 = t0v[o0 + 2], sh3 = t0v[o0 + 3];
        int chunk = ((o0 >> 3) ^ px7);
#pragma unroll
        for (int pt = 0; pt < 2; ++pt) {
            int p = pt * 16 + ml;
            float z0 = fmaxf(fmaf(acc1[ot][pt][0], sc0, sh0), 0.f);
            float z1 = fmaxf(fmaf(acc1[ot][pt][1], sc1, sh1), 0.f);
            float z2 = fmaxf(fmaf(acc1[ot][pt][2], sc2, sh2), 0.f);
            float z3 = fmaxf(fmaf(acc1[ot][pt][3], sc3, sh3), 0.f);
            u32 lo = f2h(z0) | ((u32)f2h(z1) << 16);
            u32 hi = f2h(z2) | ((u32)f2h(z3) << 16);
            *(uint2*)&sx[p * HID + chunk * 8 + (o0 & 7)] = make_uint2(lo, hi);
        }
    }
    __syncthreads();

    // ---------------- GEMM2: h2 = W1 @ h1 ----------------
    v4f acc2[4][2];
#pragma unroll
    for (int ot = 0; ot < 4; ++ot)
        for (int pt = 0; pt < 2; ++pt)
            acc2[ot][pt] = (v4f){0.f, 0.f, 0.f, 0.f};

#pragma unroll
    for (int s = 0; s < 8; ++s) {
        int kc = s * 4 + ql;
        int pc = (kc ^ px7) * 8;
        v8h bf0 = __builtin_bit_cast(v8h, *(const uint4*)&sx[ml * HID + pc]);
        v8h bf1 = __builtin_bit_cast(v8h, *(const uint4*)&sx[(16 + ml) * HID + pc]);
#pragma unroll
        for (int ot = 0; ot < 4; ++ot) {
            int o = w * 64 + ot * 16 + ml;
            v8h af = __builtin_bit_cast(v8h, W1v[o * 32 + kc]);
            acc2[ot][0] = __builtin_amdgcn_mfma_f32_16x16x32_f16(af, bf0, acc2[ot][0], 0, 0, 0);
            acc2[ot][1] = __builtin_amdgcn_mfma_f32_16x16x32_f16(af, bf1, acc2[ot][1], 0, 0, 0);
        }
    }

    // epilogue 2: BN + ReLU (via max with 0) + channel max over this wave's 64 o
    const float* s1v = sst + 512;
    const float* t1v = sst + 768;
    float mx0 = 0.f, mx1 = 0.f;   // relu floor = 0
#pragma unroll
    for (int ot = 0; ot < 4; ++ot) {
        int o0 = w * 64 + ot * 16 + ql * 4;
#pragma unroll
        for (int r = 0; r < 4; ++r) {
            float sc = s1v[o0 + r], sh = t1v[o0 + r];
            mx0 = fmaxf(mx0, fmaf(acc2[ot][0][r], sc, sh));
            mx1 = fmaxf(mx1, fmaf(acc2[ot][1][r], sc, sh));
        }
    }
    mx0 = fmaxf(mx0, __shfl_xor(mx0, 16, 64));
    mx0 = fmaxf(mx0, __shfl_xor(mx0, 32, 64));
    mx1 = fmaxf(mx1, __shfl_xor(mx1, 16, 64));
    mx1 = fmaxf(mx1, __shfl_xor(mx1, 32, 64));
    if (lane < 16) {
        sred[w][ml]      = mx0;
        sred[w][16 + ml] = mx1;
    }
    __syncthreads();
    if (tid < 32)
        out[(size_t)b * N1 + n0 + tid] =
            fmaxf(fmaxf(sred[0][tid], sred[1][tid]),
                  fmaxf(sred[2][tid], sred[3][tid]));
}

// =====================================================================
extern "C" void kernel_launch(void* const* d_in, const int* in_sizes, int n_in,
                              void* d_out, int out_size, void* d_ws, size_t ws_size,
                              hipStream_t stream)
{
    const float* xyz1     = (const float*)d_in[0];
    const float* xyz2     = (const float*)d_in[1];
    const float* points2  = (const float*)d_in[2];
    const float* points1  = (const float*)d_in[3];
    const float* pointsb1 = (const float*)d_in[4];
    const float* w0   = (const float*)d_in[5];
    const float* b0   = (const float*)d_in[6];
    const float* g0   = (const float*)d_in[7];
    const float* be0  = (const float*)d_in[8];
    const float* m0   = (const float*)d_in[9];
    const float* v0   = (const float*)d_in[10];
    const float* w1   = (const float*)d_in[11];
    const float* b1   = (const float*)d_in[12];
    const float* g1   = (const float*)d_in[13];
    const float* be1  = (const float*)d_in[14];
    const float* m1   = (const float*)d_in[15];
    const float* v1   = (const float*)d_in[16];
    float* out = (float*)d_out;

    char* ws = (char*)d_ws;
    u16*    W0h   = (u16*)(ws + 0);
    u16*    W1h   = (u16*)(ws + 196608);
    float*  sst   = (float*)(ws + 327680);
    float4* xyz2q = (float4*)(ws + 331776);
    int*    idx3  = (int*)(ws + 593920);
    float*  w3    = (float*)(ws + 1380352);
    float*  p2t   = (float*)(ws + 2166784);

    prep_kernel<<<706, 256, 0, stream>>>(w0, w1, b0, g0, be0, m0, v0,
                                         b1, g1, be1, m1, v1, xyz2,
                                         W0h, W1h, sst, xyz2q);
    transpose_kernel<<<dim3(64, 4, 4), 256, 0, stream>>>(points2, p2t);
    knn_kernel<<<dim3(256, 4), 256, 0, stream>>>(xyz1, xyz2q, idx3, w3);
    mlp_kernel<<<dim3(512, 4), 256, 0, stream>>>(points1, pointsb1,
                                                 (const float4*)p2t, idx3, w3,
                                                 (const uint4*)W0h, (const uint4*)W1h,
                                                 sst, out);
}

// Round 10
// 320.487 us; speedup vs baseline: 1.2666x; 1.0217x over previous
//
#include <hip/hip_runtime.h>

#define N1 16384
#define N2 4096
#define CC 128
#define KIN 384
#define HID 256

typedef unsigned short u16;
typedef unsigned int u32;

typedef _Float16 v8h __attribute__((ext_vector_type(8)));
typedef float v4f __attribute__((ext_vector_type(4)));

// ---------- workspace layout (bytes) ----------
// W0h  fp16 256x384           @ 0        (196608)
// W1h  fp16 256x256           @ 196608   (131072)
// sst  fp32 s0,t0,s1,t1 x256  @ 327680   (4096)
// xyz2q float4 B*N2           @ 331776   (262144)
// idx3 int B*N1*3             @ 593920   (786432)
// w3   fp32 B*N1*3            @ 1380352  (786432)
// p2t  fp32 B*N2*C            @ 2166784  (8388608)
// total = 10555392

__device__ __forceinline__ u16 f2h(float f) {
    _Float16 h = (_Float16)f;
    return __builtin_bit_cast(u16, h);
}

// =====================================================================
// Prep: convert weights to fp16, fold BN into scale/shift, build xyz2q
// =====================================================================
__global__ __launch_bounds__(256) void prep_kernel(
    const float* __restrict__ w0, const float* __restrict__ w1,
    const float* __restrict__ b0, const float* __restrict__ g0, const float* __restrict__ be0,
    const float* __restrict__ m0, const float* __restrict__ v0,
    const float* __restrict__ b1, const float* __restrict__ g1, const float* __restrict__ be1,
    const float* __restrict__ m1, const float* __restrict__ v1,
    const float* __restrict__ xyz2,
    u16* __restrict__ W0h, u16* __restrict__ W1h,
    float* __restrict__ sst, float4* __restrict__ xyz2q)
{
    int id = blockIdx.x * 256 + threadIdx.x;
    if (id < 98304) {
        W0h[id] = f2h(w0[id]);
    } else if (id < 163840) {
        int t = id - 98304;
        W1h[t] = f2h(w1[t]);
    } else if (id < 164352) {
        int t = id - 163840;
        int o = t & 255;
        if (t < 256) {
            float s = g0[o] * rsqrtf(v0[o] + 1e-5f);
            sst[o]       = s;
            sst[256 + o] = (b0[o] - m0[o]) * s + be0[o];
        } else {
            float s = g1[o] * rsqrtf(v1[o] + 1e-5f);
            sst[512 + o] = s;
            sst[768 + o] = (b1[o] - m1[o]) * s + be1[o];
        }
    } else if (id < 180736) {
        int t = id - 164352;  // b*N2+n
        float x = xyz2[(size_t)t * 3 + 0];
        float y = xyz2[(size_t)t * 3 + 1];
        float z = xyz2[(size_t)t * 3 + 2];
        xyz2q[t] = make_float4(x, y, z, fmaf(x, x, fmaf(y, y, z * z)));
    }
}

// =====================================================================
// Transpose points2 (B,C,N2) -> p2t (B,N2,C)
// 128ch x 64n2 tile, LDS pad +1 (2-way = free): reads 256B segments,
// writes FULL 512B rows (old version wrote 128B segments).
// =====================================================================
__global__ __launch_bounds__(256) void transpose_kernel(
    const float* __restrict__ points2, float* __restrict__ p2t)
{
    __shared__ float tile[64][129];   // 33024 B
    int n20 = blockIdx.x * 64;
    int b   = blockIdx.y;
    int tid = threadIdx.x;

    int jr = tid & 63, cr = tid >> 6;        // read: 4 ch x 64 n2 per iter
#pragma unroll 8
    for (int it = 0; it < 32; ++it) {
        int ch = it * 4 + cr;
        tile[jr][ch] = points2[((size_t)b * CC + ch) * N2 + n20 + jr];
    }
    __syncthreads();

    int cw = tid & 127, jw0 = tid >> 7;      // write: 2 rows x 128 ch per iter
#pragma unroll 8
    for (int it = 0; it < 32; ++it) {
        int j = it * 2 + jw0;
        p2t[((size_t)b * N2 + n20 + j) * CC + cw] = tile[j][cw];
    }
}

// =====================================================================
// 3-NN + inverse-distance weights
// 256 thr / block, 32 queries / block, 2 queries / thread (named scalars),
// 16-way candidate split; candidates staged in 4 stages x 1024 float4
// (16 KB LDS). Grid 2048 = 8 blocks/CU, waves_per_eu(8,8) -> 8 waves/SIMD
// (R9 evidence: 4 waves left ~50% issue stall; real VALUBusy is half the
// reported gfx94x-formula value). State ~35 VGPR fits 64-VGPR budget.
// =====================================================================
#define BINS(t, cand, D0, D1, D2, I0, I1, I2) do {                    \
    bool c0 = (t) < (D0);                                             \
    bool c1 = (t) < (D1);                                             \
    bool c2 = (t) < (D2);                                             \
    I2 = c1 ? (I1) : (c2 ? (cand) : (I2));   /* old I1 */             \
    I1 = c0 ? (I0) : (c1 ? (cand) : (I1));   /* old I0 */             \
    I0 = c0 ? (cand) : (I0);                                          \
    D2 = __builtin_amdgcn_fmed3f((D1), (t), (D2));  /* old D1 */      \
    D1 = __builtin_amdgcn_fmed3f((D0), (t), (D1));  /* old D0 */      \
    D0 = fminf((t), (D0));                                            \
} while (0)

#define INS3LEX(t, j, D0, D1, D2, I0, I1, I2) do {                    \
    bool lt2 = (t) < (D2) || ((t) == (D2) && (j) < (I2));             \
    bool lt1 = (t) < (D1) || ((t) == (D1) && (j) < (I1));             \
    bool lt0 = (t) < (D0) || ((t) == (D0) && (j) < (I0));             \
    if (lt2) {                                                        \
        if (lt1) {                                                    \
            D2 = (D1); I2 = (I1);                                     \
            if (lt0) { D1 = (D0); I1 = (I0); D0 = (t); I0 = (j); }    \
            else     { D1 = (t); I1 = (j); }                          \
        } else { D2 = (t); I2 = (j); }                                \
    }                                                                 \
} while (0)

#define MERGE_STEP(st, D0, D1, D2, I0, I1, I2) do {                   \
    float e0 = __shfl_xor((D0), (st), 64);                            \
    float e1 = __shfl_xor((D1), (st), 64);                            \
    float e2 = __shfl_xor((D2), (st), 64);                            \
    int   j0 = __shfl_xor((I0), (st), 64);                            \
    int   j1 = __shfl_xor((I1), (st), 64);                            \
    int   j2 = __shfl_xor((I2), (st), 64);                            \
    INS3LEX(e0, j0, D0, D1, D2, I0, I1, I2);                          \
    INS3LEX(e1, j1, D0, D1, D2, I0, I1, I2);                          \
    INS3LEX(e2, j2, D0, D1, D2, I0, I1, I2);                          \
} while (0)

#define KNN_OUT(Q, D0, D1, D2, I0, I1, I2, PP) do {                   \
    float r0 = 1.f / ((D0) + (PP));                                   \
    float r1 = 1.f / ((D1) + (PP));                                   \
    float r2 = 1.f / ((D2) + (PP));                                   \
    float inv = 1.f / (r0 + r1 + r2);                                 \
    size_t o3 = ((size_t)b * N1 + p0 + (Q)) * 3;                      \
    idx3[o3]     = (I0);                                              \
    idx3[o3 + 1] = (I1);                                              \
    idx3[o3 + 2] = (I2);                                              \
    w3[o3]     = r0 * inv;                                            \
    w3[o3 + 1] = r1 * inv;                                            \
    w3[o3 + 2] = r2 * inv;                                            \
} while (0)

__global__ __launch_bounds__(256)
__attribute__((amdgpu_waves_per_eu(8, 8)))
void knn_kernel(
    const float* __restrict__ xyz1, const float4* __restrict__ xyz2q,
    int* __restrict__ idx3, float* __restrict__ w3)
{
    __shared__ float4 slds[1024];   // 16384 B

    int tid = threadIdx.x;
    int b   = blockIdx.y;
    int n0  = blockIdx.x * 32;

    int s  = tid & 15;      // candidate split (lane bits 0..3)
    int g  = tid >> 4;      // query group 0..15
    int p0 = n0 + g * 2;

    size_t pb = ((size_t)b * N1 + p0) * 3;
    float x0 = xyz1[pb + 0], y0 = xyz1[pb + 1], z0 = xyz1[pb + 2];
    float x1 = xyz1[pb + 3], y1 = xyz1[pb + 4], z1 = xyz1[pb + 5];
    float ax0 = -2.f * x0, ay0 = -2.f * y0, az0 = -2.f * z0;
    float ax1 = -2.f * x1, ay1 = -2.f * y1, az1 = -2.f * z1;
    float pp0 = fmaf(x0, x0, fmaf(y0, y0, z0 * z0));
    float pp1 = fmaf(x1, x1, fmaf(y1, y1, z1 * z1));

    float da0 = 1e30f, da1 = 1e30f, da2 = 1e30f;
    float db0 = 1e30f, db1 = 1e30f, db2 = 1e30f;
    int   ia0 = 0, ia1 = 0, ia2 = 0;
    int   ib0 = 0, ib1 = 0, ib2 = 0;

#pragma unroll
    for (int stage = 0; stage < 4; ++stage) {
        int base = stage * 1024;
        // stage candidates to LDS (coalesced 16B)
#pragma unroll
        for (int i = 0; i < 4; ++i)
            slds[tid + i * 256] = xyz2q[(size_t)b * N2 + base + tid + i * 256];
        __syncthreads();

        // thread s scans candidates s, s+16, ... ascending across stages ->
        // strict < keeps lowest-index-on-tie, matching stable top_k.
#pragma unroll 4
        for (int k = 0; k < 64; ++k) {
            int c = s + (k << 4);
            float4 v = slds[c];
            int cand = base + c;
            float t0 = fmaf(ax0, v.x, fmaf(ay0, v.y, fmaf(az0, v.z, v.w)));
            float t1 = fmaf(ax1, v.x, fmaf(ay1, v.y, fmaf(az1, v.z, v.w)));
            BINS(t0, cand, da0, da1, da2, ia0, ia1, ia2);
            BINS(t1, cand, db0, db1, db2, ib0, ib1, ib2);
        }
        __syncthreads();   // protect LDS overwrite by next stage
    }

    // butterfly merge across the 16 splits (lex tie-break by true index)
#pragma unroll
    for (int st = 1; st <= 8; st <<= 1) {
        MERGE_STEP(st, da0, da1, da2, ia0, ia1, ia2);
        MERGE_STEP(st, db0, db1, db2, ib0, ib1, ib2);
    }

    if (s == 0) {
        KNN_OUT(0, da0, da1, da2, ia0, ia1, ia2, pp0);
        KNN_OUT(1, db0, db1, db2, ib0, ib1, ib2, pp1);
    }
}

// =====================================================================
// Fused interpolate + concat + MLP(384->256->256, BN+ReLU) + channel max
// 32-POINT TILE (R9 structure -- unchanged this round)
// =====================================================================
__global__ __launch_bounds__(256)
__attribute__((amdgpu_waves_per_eu(5, 5)))
void mlp_kernel(
    const float* __restrict__ points1, const float* __restrict__ pointsb1,
    const float4* __restrict__ p2t4,
    const int* __restrict__ idx3, const float* __restrict__ w3,
    const uint4* __restrict__ W0v, const uint4* __restrict__ W1v,
    const float* __restrict__ sst, float* __restrict__ out)
{
    // x: 32 rows x 384 fp16, 16B-chunk swizzled by (p&7); h1 overlays (32x256)
    __shared__ __align__(16) u16 sx[32 * KIN];   // 24576 B
    __shared__ float sred[4][32];
    __shared__ int   s_idx[96];
    __shared__ float s_w[96];

    int tid = threadIdx.x;
    int b   = blockIdx.y;
    int n0  = blockIdx.x * 32;

    if (tid < 96) {
        size_t gi = ((size_t)b * N1 + n0) * 3 + tid;
        s_idx[tid] = idx3[gi];
        s_w[tid]   = w3[gi];
    }

    // ---- stage x rows 0..127 (points1) + 256..383 (points_b1) ----
    int pL = tid & 31;
    int t4 = (tid >> 5) * 4;          // 0,4,...,28
#pragma unroll
    for (int k = 0; k < 4; ++k) {
        int r4 = t4 + 32 * k;
        size_t base = ((size_t)b * CC + r4) * N1 + n0 + pL;
        float a0 = points1[base];
        float a1 = points1[base + (size_t)N1];
        float a2 = points1[base + (size_t)2 * N1];
        float a3 = points1[base + (size_t)3 * N1];
        u32 lo = f2h(a0) | ((u32)f2h(a1) << 16);
        u32 hi = f2h(a2) | ((u32)f2h(a3) << 16);
        int chunk = (r4 >> 3) ^ (pL & 7);
        *(uint2*)&sx[pL * KIN + chunk * 8 + (r4 & 7)] = make_uint2(lo, hi);
    }
#pragma unroll
    for (int k = 0; k < 4; ++k) {
        int r4 = t4 + 32 * k;
        int k4 = 256 + r4;
        size_t base = ((size_t)b * CC + r4) * N1 + n0 + pL;
        float a0 = pointsb1[base];
        float a1 = pointsb1[base + (size_t)N1];
        float a2 = pointsb1[base + (size_t)2 * N1];
        float a3 = pointsb1[base + (size_t)3 * N1];
        u32 lo = f2h(a0) | ((u32)f2h(a1) << 16);
        u32 hi = f2h(a2) | ((u32)f2h(a3) << 16);
        int chunk = (k4 >> 3) ^ (pL & 7);
        *(uint2*)&sx[pL * KIN + chunk * 8 + (k4 & 7)] = make_uint2(lo, hi);
    }
    __syncthreads();   // s_idx/s_w visible for gather

    // ---- stage x rows 128..255: 3-NN interpolation from p2t rows ----
    int c4  = tid & 31;
    int pg  = tid >> 5;
    int k4g = 128 + c4 * 4;
#pragma unroll
    for (int k = 0; k < 4; ++k) {
        int p = pg + 8 * k;
        float w0w = s_w[p * 3 + 0], w1w = s_w[p * 3 + 1], w2w = s_w[p * 3 + 2];
        float4 f0 = p2t4[((size_t)b * N2 + s_idx[p * 3 + 0]) * 32 + c4];
        float4 f1 = p2t4[((size_t)b * N2 + s_idx[p * 3 + 1]) * 32 + c4];
        float4 f2 = p2t4[((size_t)b * N2 + s_idx[p * 3 + 2]) * 32 + c4];
        float e0 = fmaf(w0w, f0.x, fmaf(w1w, f1.x, w2w * f2.x));
        float e1 = fmaf(w0w, f0.y, fmaf(w1w, f1.y, w2w * f2.y));
        float e2 = fmaf(w0w, f0.z, fmaf(w1w, f1.z, w2w * f2.z));
        float e3 = fmaf(w0w, f0.w, fmaf(w1w, f1.w, w2w * f2.w));
        u32 lo = f2h(e0) | ((u32)f2h(e1) << 16);
        u32 hi = f2h(e2) | ((u32)f2h(e3) << 16);
        int chunk = (k4g >> 3) ^ (p & 7);
        *(uint2*)&sx[p * KIN + chunk * 8 + (k4g & 7)] = make_uint2(lo, hi);
    }
    __syncthreads();

    int lane = tid & 63, w = tid >> 6;      // wave w: o in [w*64, w*64+64)
    int ml = lane & 15, ql = lane >> 4;     // frag row/col, quad
    int px7 = ml & 7;                       // == p&7 for both pt (p=pt*16+ml)

    // ---------------- GEMM1: h1 = W0 @ x ----------------
    v4f acc1[4][2];
#pragma unroll
    for (int ot = 0; ot < 4; ++ot)
        for (int pt = 0; pt < 2; ++pt)
            acc1[ot][pt] = (v4f){0.f, 0.f, 0.f, 0.f};

#pragma unroll
    for (int s = 0; s < 12; ++s) {
        int kc = s * 4 + ql;
        int pc = (kc ^ px7) * 8;
        v8h bf0 = __builtin_bit_cast(v8h, *(const uint4*)&sx[ml * KIN + pc]);
        v8h bf1 = __builtin_bit_cast(v8h, *(const uint4*)&sx[(16 + ml) * KIN + pc]);
#pragma unroll
        for (int ot = 0; ot < 4; ++ot) {
            int o = w * 64 + ot * 16 + ml;
            v8h af = __builtin_bit_cast(v8h, W0v[o * 48 + kc]);
            acc1[ot][0] = __builtin_amdgcn_mfma_f32_16x16x32_f16(af, bf0, acc1[ot][0], 0, 0, 0);
            acc1[ot][1] = __builtin_amdgcn_mfma_f32_16x16x32_f16(af, bf1, acc1[ot][1], 0, 0, 0);
        }
    }
    __syncthreads();   // all x reads done before h1 overlays sx

    // epilogue 1: BN+ReLU -> fp16 h1[p][o] (row stride 256, swizzled)
    const float* s0v = sst;
    const float* t0v = sst + 256;
#pragma unroll
    for (int ot = 0; ot < 4; ++ot) {
        int o0 = w * 64 + ot * 16 + ql * 4;
        float sc0 = s0v[o0], sc1 = s0v[o0 + 1], sc2 = s0v[o0 + 2], sc3 = s0v[o0 + 3];
        float sh0 = t0v[o0], sh1 = t0v[o0 + 1], sh2 = t0v[o0 + 2], sh3 = t0v[o0 + 3];
        int chunk = ((o0 >> 3) ^ px7);
#pragma unroll
        for (int pt = 0; pt < 2; ++pt) {
            int p = pt * 16 + ml;
            float z0 = fmaxf(fmaf(acc1[ot][pt][0], sc0, sh0), 0.f);
            float z1 = fmaxf(fmaf(acc1[ot][pt][1], sc1, sh1), 0.f);
            float z2 = fmaxf(fmaf(acc1[ot][pt][2], sc2, sh2), 0.f);
            float z3 = fmaxf(fmaf(acc1[ot][pt][3], sc3, sh3), 0.f);
            u32 lo = f2h(z0) | ((u32)f2h(z1) << 16);
            u32 hi = f2h(z2) | ((u32)f2h(z3) << 16);
            *(uint2*)&sx[p * HID + chunk * 8 + (o0 & 7)] = make_uint2(lo, hi);
        }
    }
    __syncthreads();

    // ---------------- GEMM2: h2 = W1 @ h1 ----------------
    v4f acc2[4][2];
#pragma unroll
    for (int ot = 0; ot < 4; ++ot)
        for (int pt = 0; pt < 2; ++pt)
            acc2[ot][pt] = (v4f){0.f, 0.f, 0.f, 0.f};

#pragma unroll
    for (int s = 0; s < 8; ++s) {
        int kc = s * 4 + ql;
        int pc = (kc ^ px7) * 8;
        v8h bf0 = __builtin_bit_cast(v8h, *(const uint4*)&sx[ml * HID + pc]);
        v8h bf1 = __builtin_bit_cast(v8h, *(const uint4*)&sx[(16 + ml) * HID + pc]);
#pragma unroll
        for (int ot = 0; ot < 4; ++ot) {
            int o = w * 64 + ot * 16 + ml;
            v8h af = __builtin_bit_cast(v8h, W1v[o * 32 + kc]);
            acc2[ot][0] = __builtin_amdgcn_mfma_f32_16x16x32_f16(af, bf0, acc2[ot][0], 0, 0, 0);
            acc2[ot][1] = __builtin_amdgcn_mfma_f32_16x16x32_f16(af, bf1, acc2[ot][1], 0, 0, 0);
        }
    }

    // epilogue 2: BN + ReLU (via max with 0) + channel max over this wave's 64 o
    const float* s1v = sst + 512;
    const float* t1v = sst + 768;
    float mx0 = 0.f, mx1 = 0.f;   // relu floor = 0
#pragma unroll
    for (int ot = 0; ot < 4; ++ot) {
        int o0 = w * 64 + ot * 16 + ql * 4;
#pragma unroll
        for (int r = 0; r < 4; ++r) {
            float sc = s1v[o0 + r], sh = t1v[o0 + r];
            mx0 = fmaxf(mx0, fmaf(acc2[ot][0][r], sc, sh));
            mx1 = fmaxf(mx1, fmaf(acc2[ot][1][r], sc, sh));
        }
    }
    mx0 = fmaxf(mx0, __shfl_xor(mx0, 16, 64));
    mx0 = fmaxf(mx0, __shfl_xor(mx0, 32, 64));
    mx1 = fmaxf(mx1, __shfl_xor(mx1, 16, 64));
    mx1 = fmaxf(mx1, __shfl_xor(mx1, 32, 64));
    if (lane < 16) {
        sred[w][ml]      = mx0;
        sred[w][16 + ml] = mx1;
    }
    __syncthreads();
    if (tid < 32)
        out[(size_t)b * N1 + n0 + tid] =
            fmaxf(fmaxf(sred[0][tid], sred[1][tid]),
                  fmaxf(sred[2][tid], sred[3][tid]));
}

// =====================================================================
extern "C" void kernel_launch(void* const* d_in, const int* in_sizes, int n_in,
                              void* d_out, int out_size, void* d_ws, size_t ws_size,
                              hipStream_t stream)
{
    const float* xyz1     = (const float*)d_in[0];
    const float* xyz2     = (const float*)d_in[1];
    const float* points2  = (const float*)d_in[2];
    const float* points1  = (const float*)d_in[3];
    const float* pointsb1 = (const float*)d_in[4];
    const float* w0   = (const float*)d_in[5];
    const float* b0   = (const float*)d_in[6];
    const float* g0   = (const float*)d_in[7];
    const float* be0  = (const float*)d_in[8];
    const float* m0   = (const float*)d_in[9];
    const float* v0   = (const float*)d_in[10];
    const float* w1   = (const float*)d_in[11];
    const float* b1   = (const float*)d_in[12];
    const float* g1   = (const float*)d_in[13];
    const float* be1  = (const float*)d_in[14];
    const float* m1   = (const float*)d_in[15];
    const float* v1   = (const float*)d_in[16];
    float* out = (float*)d_out;

    char* ws = (char*)d_ws;
    u16*    W0h   = (u16*)(ws + 0);
    u16*    W1h   = (u16*)(ws + 196608);
    float*  sst   = (float*)(ws + 327680);
    float4* xyz2q = (float4*)(ws + 331776);
    int*    idx3  = (int*)(ws + 593920);
    float*  w3    = (float*)(ws + 1380352);
    float*  p2t   = (float*)(ws + 2166784);

    prep_kernel<<<706, 256, 0, stream>>>(w0, w1, b0, g0, be0, m0, v0,
                                         b1, g1, be1, m1, v1, xyz2,
                                         W0h, W1h, sst, xyz2q);
    transpose_kernel<<<dim3(64, 4), 256, 0, stream>>>(points2, p2t);
    knn_kernel<<<dim3(512, 4), 256, 0, stream>>>(xyz1, xyz2q, idx3, w3);
    mlp_kernel<<<dim3(512, 4), 256, 0, stream>>>(points1, pointsb1,
                                                 (const float4*)p2t, idx3, w3,
                                                 (const uint4*)W0h, (const uint4*)W1h,
                                                 sst, out);
}